// Round 1
// baseline (18595.918 us; speedup 1.0000x reference)
//
#include <hip/hip_runtime.h>
#include <cstdint>
#include <cstddef>

#define DEV static __device__ __forceinline__

namespace {
constexpr int NB     = 8;
constexpr int NT     = 1024;
constexpr int NMEL   = 96;
constexpr int NDIM   = 192;    // mels * 2 after flux concat
constexpr int NCH    = 32;
constexpr int DMODEL = 1536;
constexpr int DINNER = 3072;
constexpr int DSTATE = 16;
constexpr int DTRANK = 96;
constexpr int NLAYER = 4;
constexpr int NCLASS = 5;
constexpr int MROWS  = NB * NT;   // 8192
}

DEV float siluf(float x)    { return x / (1.0f + __expf(-x)); }
DEV float softplusf(float x){ return fmaxf(x, 0.0f) + log1pf(__expf(-fabsf(x))); }

// ---------------- prep: x -> hcat (B,192,T): [x ; relu(diff)] ----------------
__global__ __launch_bounds__(256) void k_prep(const float* __restrict__ x,
                                              float* __restrict__ hcat)
{
    int idx = blockIdx.x * 256 + threadIdx.x;
    if (idx >= NB * NDIM * NT) return;
    int t = idx & (NT - 1);
    int m = (idx >> 10) % NDIM;
    int b = idx / (NDIM * NT);
    float v;
    if (m < NMEL) {
        v = x[((size_t)b * NMEL + m) * NT + t];
    } else {
        int mm = m - NMEL;
        v = 0.f;
        if (t > 0) {
            const float* p = x + ((size_t)b * NMEL + mm) * NT + t;
            v = fmaxf(p[0] - p[-1], 0.f);
        }
    }
    hcat[idx] = v;
}

// ---------------- conv1a (1->32, 3x3) + silu ----------------
__global__ __launch_bounds__(256) void k_conv1a(const float* __restrict__ hcat,
    const float* __restrict__ w, const float* __restrict__ bias,
    float* __restrict__ out)   // (B,32,192,T)
{
    int idx = blockIdx.x * 256 + threadIdx.x;
    if (idx >= NB * NDIM * NT) return;
    int t = idx & (NT - 1);
    int h = (idx >> 10) % NDIM;
    int b = idx / (NDIM * NT);
    float in[3][3];
    #pragma unroll
    for (int dh = 0; dh < 3; ++dh)
        #pragma unroll
        for (int dw = 0; dw < 3; ++dw) {
            int hh = h + dh - 1, tt = t + dw - 1;
            in[dh][dw] = (hh >= 0 && hh < NDIM && tt >= 0 && tt < NT)
                       ? hcat[((size_t)b * NDIM + hh) * NT + tt] : 0.f;
        }
    for (int c = 0; c < NCH; ++c) {
        float acc = bias[c];
        #pragma unroll
        for (int dh = 0; dh < 3; ++dh)
            #pragma unroll
            for (int dw = 0; dw < 3; ++dw)
                acc = fmaf(in[dh][dw], w[c * 9 + dh * 3 + dw], acc);
        out[(((size_t)b * NCH + c) * NDIM + h) * NT + t] = siluf(acc);
    }
}

// ------- conv1b (32->32 3x3) + 1x1-skip(hcat) + silu + maxpool(2,1) -------
__global__ __launch_bounds__(256) void k_conv1b_pool(
    const float* __restrict__ t1, const float* __restrict__ hcat,
    const float* __restrict__ w, const float* __restrict__ bias,
    const float* __restrict__ sw, const float* __restrict__ sb,
    float* __restrict__ out)   // (B,32,96,T)
{
    __shared__ float sT[NCH][4][66];
    const int w0 = blockIdx.x * 64;
    const int ho = blockIdx.y;            // 0..95
    const int b  = blockIdx.z;
    const int tid = threadIdx.x;
    for (int e = tid; e < NCH * 4 * 66; e += 256) {
        int wc = e % 66;
        int r  = e / 66;
        int hr = r & 3;
        int ci = r >> 2;
        int h  = 2 * ho - 1 + hr;
        int tt = w0 - 1 + wc;
        float v = 0.f;
        if (h >= 0 && h < NDIM && tt >= 0 && tt < NT)
            v = t1[(((size_t)b * NCH + ci) * NDIM + h) * NT + tt];
        sT[ci][hr][wc] = v;
    }
    __syncthreads();
    const int wl   = tid & 63;
    const int slot = tid >> 6;     // wave-uniform
    float acc0[8], acc1[8];
    #pragma unroll
    for (int j = 0; j < 8; ++j) { acc0[j] = bias[slot * 8 + j]; acc1[j] = acc0[j]; }
    for (int ci = 0; ci < NCH; ++ci) {
        #pragma unroll
        for (int dh = 0; dh < 3; ++dh) {
            #pragma unroll
            for (int dw = 0; dw < 3; ++dw) {
                float v0 = sT[ci][dh    ][wl + dw];
                float v1 = sT[ci][dh + 1][wl + dw];
                #pragma unroll
                for (int j = 0; j < 8; ++j) {
                    float wg = w[((slot * 8 + j) * NCH + ci) * 9 + dh * 3 + dw];
                    acc0[j] = fmaf(v0, wg, acc0[j]);
                    acc1[j] = fmaf(v1, wg, acc1[j]);
                }
            }
        }
    }
    float hc0 = hcat[((size_t)b * NDIM + 2 * ho    ) * NT + w0 + wl];
    float hc1 = hcat[((size_t)b * NDIM + 2 * ho + 1) * NT + w0 + wl];
    #pragma unroll
    for (int j = 0; j < 8; ++j) {
        int c = slot * 8 + j;
        float r0 = siluf(acc0[j] + fmaf(hc0, sw[c], sb[c]));
        float r1 = siluf(acc1[j] + fmaf(hc1, sw[c], sb[c]));
        out[(((size_t)b * NCH + c) * NMEL + ho) * NT + w0 + wl] = fmaxf(r0, r1);
    }
}

// ---------------- conv2a (32->32 3x3) + silu, two rows per block ----------------
__global__ __launch_bounds__(256) void k_conv2a(
    const float* __restrict__ p1, const float* __restrict__ w,
    const float* __restrict__ bias, float* __restrict__ out)  // (B,32,96,T)
{
    __shared__ float sT[NCH][4][66];
    const int w0 = blockIdx.x * 64;
    const int ht = blockIdx.y;            // 0..47 -> rows 2ht, 2ht+1
    const int b  = blockIdx.z;
    const int tid = threadIdx.x;
    for (int e = tid; e < NCH * 4 * 66; e += 256) {
        int wc = e % 66;
        int r  = e / 66;
        int hr = r & 3;
        int ci = r >> 2;
        int h  = 2 * ht - 1 + hr;
        int tt = w0 - 1 + wc;
        float v = 0.f;
        if (h >= 0 && h < NMEL && tt >= 0 && tt < NT)
            v = p1[(((size_t)b * NCH + ci) * NMEL + h) * NT + tt];
        sT[ci][hr][wc] = v;
    }
    __syncthreads();
    const int wl   = tid & 63;
    const int slot = tid >> 6;
    float acc0[8], acc1[8];
    #pragma unroll
    for (int j = 0; j < 8; ++j) { acc0[j] = bias[slot * 8 + j]; acc1[j] = acc0[j]; }
    for (int ci = 0; ci < NCH; ++ci) {
        #pragma unroll
        for (int dh = 0; dh < 3; ++dh) {
            #pragma unroll
            for (int dw = 0; dw < 3; ++dw) {
                float v0 = sT[ci][dh    ][wl + dw];
                float v1 = sT[ci][dh + 1][wl + dw];
                #pragma unroll
                for (int j = 0; j < 8; ++j) {
                    float wg = w[((slot * 8 + j) * NCH + ci) * 9 + dh * 3 + dw];
                    acc0[j] = fmaf(v0, wg, acc0[j]);
                    acc1[j] = fmaf(v1, wg, acc1[j]);
                }
            }
        }
    }
    #pragma unroll
    for (int j = 0; j < 8; ++j) {
        int c = slot * 8 + j;
        out[(((size_t)b * NCH + c) * NMEL + 2 * ht    ) * NT + w0 + wl] = siluf(acc0[j]);
        out[(((size_t)b * NCH + c) * NMEL + 2 * ht + 1) * NT + w0 + wl] = siluf(acc1[j]);
    }
}

// ------- conv2b (32->32 3x3) + identity-skip(p1) + silu + maxpool -------
__global__ __launch_bounds__(256) void k_conv2b_pool(
    const float* __restrict__ t3, const float* __restrict__ p1,
    const float* __restrict__ w, const float* __restrict__ bias,
    float* __restrict__ out)   // (B,32,48,T)
{
    __shared__ float sT[NCH][4][66];
    const int w0 = blockIdx.x * 64;
    const int ho = blockIdx.y;            // 0..47
    const int b  = blockIdx.z;
    const int tid = threadIdx.x;
    for (int e = tid; e < NCH * 4 * 66; e += 256) {
        int wc = e % 66;
        int r  = e / 66;
        int hr = r & 3;
        int ci = r >> 2;
        int h  = 2 * ho - 1 + hr;
        int tt = w0 - 1 + wc;
        float v = 0.f;
        if (h >= 0 && h < NMEL && tt >= 0 && tt < NT)
            v = t3[(((size_t)b * NCH + ci) * NMEL + h) * NT + tt];
        sT[ci][hr][wc] = v;
    }
    __syncthreads();
    const int wl   = tid & 63;
    const int slot = tid >> 6;
    float acc0[8], acc1[8];
    #pragma unroll
    for (int j = 0; j < 8; ++j) { acc0[j] = bias[slot * 8 + j]; acc1[j] = acc0[j]; }
    for (int ci = 0; ci < NCH; ++ci) {
        #pragma unroll
        for (int dh = 0; dh < 3; ++dh) {
            #pragma unroll
            for (int dw = 0; dw < 3; ++dw) {
                float v0 = sT[ci][dh    ][wl + dw];
                float v1 = sT[ci][dh + 1][wl + dw];
                #pragma unroll
                for (int j = 0; j < 8; ++j) {
                    float wg = w[((slot * 8 + j) * NCH + ci) * 9 + dh * 3 + dw];
                    acc0[j] = fmaf(v0, wg, acc0[j]);
                    acc1[j] = fmaf(v1, wg, acc1[j]);
                }
            }
        }
    }
    #pragma unroll
    for (int j = 0; j < 8; ++j) {
        int c = slot * 8 + j;
        float sk0 = p1[(((size_t)b * NCH + c) * NMEL + 2 * ho    ) * NT + w0 + wl];
        float sk1 = p1[(((size_t)b * NCH + c) * NMEL + 2 * ho + 1) * NT + w0 + wl];
        float r0 = siluf(acc0[j] + sk0);
        float r1 = siluf(acc1[j] + sk1);
        out[(((size_t)b * NCH + c) * 48 + ho) * NT + w0 + wl] = fmaxf(r0, r1);
    }
}

// ---------------- transpose (B,1536,1024) -> (B,1024,1536) ----------------
__global__ __launch_bounds__(256) void k_transpose(const float* __restrict__ in,
                                                   float* __restrict__ out)
{
    __shared__ float tile[32][33];
    int t0 = blockIdx.x * 32;
    int d0 = blockIdx.y * 32;
    int b  = blockIdx.z;
    int tx = threadIdx.x;   // 32
    int ty = threadIdx.y;   // 8
    #pragma unroll
    for (int j = 0; j < 4; ++j)
        tile[ty + j * 8][tx] = in[((size_t)b * DMODEL + d0 + ty + j * 8) * NT + t0 + tx];
    __syncthreads();
    #pragma unroll
    for (int j = 0; j < 4; ++j)
        out[((size_t)b * NT + t0 + ty + j * 8) * DMODEL + d0 + tx] = tile[tx][ty + j * 8];
}

// ---------------- rmsnorm over D_MODEL ----------------
__global__ __launch_bounds__(256) void k_rmsnorm(const float* __restrict__ in,
    const float* __restrict__ w, float* __restrict__ out)
{
    int row = blockIdx.x;
    int tid = threadIdx.x;
    const float* p = in + (size_t)row * DMODEL;
    float v[6]; float ss = 0.f;
    #pragma unroll
    for (int j = 0; j < 6; ++j) { v[j] = p[tid + j * 256]; ss = fmaf(v[j], v[j], ss); }
    #pragma unroll
    for (int off = 1; off < 64; off <<= 1) ss += __shfl_xor(ss, off);
    __shared__ float red[4];
    int lane = tid & 63, wv = tid >> 6;
    if (lane == 0) red[wv] = ss;
    __syncthreads();
    float tot = red[0] + red[1] + red[2] + red[3];
    float sc = rsqrtf(tot * (1.0f / DMODEL) + 1e-5f);
    float* q = out + (size_t)row * DMODEL;
    #pragma unroll
    for (int j = 0; j < 6; ++j) q[tid + j * 256] = v[j] * sc * w[tid + j * 256];
}

// ---------------- generic NT GEMM: C[M,N] (+)= A[M,K] * B[N,K]^T ----------------
// EPI: 0 = store (with optional z-slab offset), 1 = softplus(acc + bias[n]), 2 = C += acc
template<int EPI>
__global__ __launch_bounds__(256) void k_gemm_nt(
    const float* __restrict__ A, int lda,
    const float* __restrict__ Bm, int ldb,
    float* __restrict__ C, int ldc,
    int K, const float* __restrict__ bias, size_t zStride)
{
    __shared__ float As[16][68];
    __shared__ float Bs[16][68];
    const int tid = threadIdx.x;
    const int tx = tid & 15, ty = tid >> 4;
    const int m0 = blockIdx.y * 64, n0 = blockIdx.x * 64;
    const int kPer = K / gridDim.z;
    const int k0 = blockIdx.z * kPer;
    const int lr = tid >> 2, lq = tid & 3;
    const float* Ap = A  + (size_t)(m0 + lr) * lda + k0 + lq * 4;
    const float* Bp = Bm + (size_t)(n0 + lr) * ldb + k0 + lq * 4;
    float acc[4][4];
    #pragma unroll
    for (int i = 0; i < 4; ++i)
        #pragma unroll
        for (int j = 0; j < 4; ++j) acc[i][j] = 0.f;
    for (int kk = 0; kk < kPer; kk += 16) {
        float4 av = *(const float4*)(Ap + kk);
        float4 bv = *(const float4*)(Bp + kk);
        __syncthreads();
        As[lq * 4 + 0][lr] = av.x; As[lq * 4 + 1][lr] = av.y;
        As[lq * 4 + 2][lr] = av.z; As[lq * 4 + 3][lr] = av.w;
        Bs[lq * 4 + 0][lr] = bv.x; Bs[lq * 4 + 1][lr] = bv.y;
        Bs[lq * 4 + 2][lr] = bv.z; Bs[lq * 4 + 3][lr] = bv.w;
        __syncthreads();
        #pragma unroll
        for (int k = 0; k < 16; ++k) {
            float4 a4 = *(const float4*)&As[k][ty * 4];
            float4 b4 = *(const float4*)&Bs[k][tx * 4];
            float a[4]  = {a4.x, a4.y, a4.z, a4.w};
            float bb[4] = {b4.x, b4.y, b4.z, b4.w};
            #pragma unroll
            for (int i = 0; i < 4; ++i)
                #pragma unroll
                for (int j = 0; j < 4; ++j)
                    acc[i][j] = fmaf(a[i], bb[j], acc[i][j]);
        }
    }
    float* Cz = C + (size_t)blockIdx.z * zStride;
    #pragma unroll
    for (int i = 0; i < 4; ++i) {
        int row = m0 + ty * 4 + i;
        float* cp = Cz + (size_t)row * ldc + n0 + tx * 4;
        if (EPI == 0) {
            float4 st = {acc[i][0], acc[i][1], acc[i][2], acc[i][3]};
            *(float4*)cp = st;
        } else if (EPI == 1) {
            const float* bp2 = bias + n0 + tx * 4;
            float4 st = { softplusf(acc[i][0] + bp2[0]), softplusf(acc[i][1] + bp2[1]),
                          softplusf(acc[i][2] + bp2[2]), softplusf(acc[i][3] + bp2[3]) };
            *(float4*)cp = st;
        } else {
            float4 old = *(const float4*)cp;
            float4 st = {old.x + acc[i][0], old.y + acc[i][1],
                         old.z + acc[i][2], old.w + acc[i][3]};
            *(float4*)cp = st;
        }
    }
}

// ---------------- depthwise causal conv1d(k=4) + bias + silu ----------------
__global__ __launch_bounds__(256) void k_conv1d(
    const float* __restrict__ xz, const float* __restrict__ w,
    const float* __restrict__ bias, float* __restrict__ u)
{
    int idx = blockIdx.x * 256 + threadIdx.x;      // over B*T*DINNER/4
    if (idx >= NB * NT * (DINNER / 4)) return;
    int dv = idx % (DINNER / 4);
    int t  = (idx / (DINNER / 4)) % NT;
    int b  = idx / ((DINNER / 4) * NT);
    int d  = dv * 4;
    const float* base = xz + ((size_t)b * NT + t) * (2 * DINNER) + d;
    float4 a[4];
    #pragma unroll
    for (int k = 0; k < 4; ++k) {
        int tm = t - 3 + k;
        if (tm >= 0) a[k] = *(const float4*)(base + (ptrdiff_t)(k - 3) * (2 * DINNER));
        else         a[k] = make_float4(0.f, 0.f, 0.f, 0.f);
    }
    float4 w0 = *(const float4*)(w + (size_t)(d + 0) * 4);
    float4 w1 = *(const float4*)(w + (size_t)(d + 1) * 4);
    float4 w2 = *(const float4*)(w + (size_t)(d + 2) * 4);
    float4 w3 = *(const float4*)(w + (size_t)(d + 3) * 4);
    float4 bb = *(const float4*)(bias + d);
    float4 o;
    o.x = siluf(bb.x + a[0].x * w0.x + a[1].x * w0.y + a[2].x * w0.z + a[3].x * w0.w);
    o.y = siluf(bb.y + a[0].y * w1.x + a[1].y * w1.y + a[2].y * w1.z + a[3].y * w1.w);
    o.z = siluf(bb.z + a[0].z * w2.x + a[1].z * w2.y + a[2].z * w2.z + a[3].z * w2.w);
    o.w = siluf(bb.w + a[0].w * w3.x + a[1].w * w3.y + a[2].w * w3.z + a[3].w * w3.w);
    *(float4*)(u + ((size_t)b * NT + t) * DINNER + d) = o;
}

// ---------------- reduce 8 split-K slabs of x_proj ----------------
__global__ __launch_bounds__(256) void k_reduce8(const float* __restrict__ part,
                                                 float* __restrict__ out)
{
    int idx = blockIdx.x * 256 + threadIdx.x;
    if (idx >= MROWS * 128) return;
    float s = 0.f;
    #pragma unroll
    for (int z = 0; z < 8; ++z) s += part[(size_t)z * MROWS * 128 + idx];
    out[idx] = s;
}

// ---------------- selective scan + gating; y written into xz u-columns ----------------
__global__ __launch_bounds__(256) void k_scan(
    const float* __restrict__ delta, const float* __restrict__ u,
    float* __restrict__ xz, const float* __restrict__ xdbl,
    const float* __restrict__ A_log, const float* __restrict__ Dp)
{
    const int tid = threadIdx.x;
    const int g = tid >> 3;           // group of 8 lanes per d
    const int i = tid & 7;            // lane: states 2i, 2i+1
    const int d = blockIdx.x * 32 + g;
    const int b = blockIdx.y;
    const float L2E = 1.44269504088896340736f;
    float aa0 = -__expf(A_log[d * DSTATE + 2 * i    ]) * L2E;
    float aa1 = -__expf(A_log[d * DSTATE + 2 * i + 1]) * L2E;
    const float dp = Dp[d];
    const float* dP = delta + (size_t)b * NT * DINNER + d;
    const float* uP = u     + (size_t)b * NT * DINNER + d;
    const float* zP = xz + (size_t)b * NT * (2 * DINNER) + DINNER + d;
    float*       yP = xz + (size_t)b * NT * (2 * DINNER) + d;
    const float* bP = xdbl + (size_t)b * NT * 128 + DTRANK + 2 * i;
    const float* cP = bP + DSTATE;
    float h0 = 0.f, h1 = 0.f;
    float dlt = *dP, uu = *uP, zz = *zP;
    float2 Bf = *(const float2*)bP;
    float2 Cf = *(const float2*)cP;
    for (int t = 0; t < NT; ++t) {
        float dlt_n = 0.f, uu_n = 0.f, zz_n = 0.f;
        float2 Bn = {0.f, 0.f}, Cn = {0.f, 0.f};
        if (t + 1 < NT) {
            dlt_n = dP[DINNER]; uu_n = uP[DINNER]; zz_n = zP[2 * DINNER];
            Bn = *(const float2*)(bP + 128); Cn = *(const float2*)(cP + 128);
        }
        float du = dlt * uu;
        float e0 = exp2f(dlt * aa0);
        float e1 = exp2f(dlt * aa1);
        h0 = fmaf(e0, h0, du * Bf.x);
        h1 = fmaf(e1, h1, du * Bf.y);
        float p = fmaf(h0, Cf.x, h1 * Cf.y);
        p += __shfl_xor(p, 1);
        p += __shfl_xor(p, 2);
        p += __shfl_xor(p, 4);
        if (i == 0)
            yP[0] = (p + uu * dp) * siluf(zz);
        dP += DINNER; uP += DINNER; zP += 2 * DINNER; yP += 2 * DINNER;
        bP += 128; cP += 128;
        dlt = dlt_n; uu = uu_n; zz = zz_n; Bf = Bn; Cf = Cn;
    }
}

// ---------------- final fc + silu + transpose to (B,5,T) ----------------
__global__ __launch_bounds__(256) void k_fc(const float* __restrict__ hR,
    const float* __restrict__ w, const float* __restrict__ bias,
    float* __restrict__ out)
{
    int row = blockIdx.x;     // b*NT + t
    int tid = threadIdx.x;
    const float* p = hR + (size_t)row * DMODEL;
    float acc[NCLASS] = {0.f, 0.f, 0.f, 0.f, 0.f};
    #pragma unroll
    for (int j = 0; j < 6; ++j) {
        int col = tid + j * 256;
        float v = p[col];
        #pragma unroll
        for (int c = 0; c < NCLASS; ++c)
            acc[c] = fmaf(v, w[c * DMODEL + col], acc[c]);
    }
    #pragma unroll
    for (int c = 0; c < NCLASS; ++c)
        #pragma unroll
        for (int off = 1; off < 64; off <<= 1)
            acc[c] += __shfl_xor(acc[c], off);
    __shared__ float red[4][NCLASS];
    int lane = tid & 63, wv = tid >> 6;
    if (lane == 0)
        for (int c = 0; c < NCLASS; ++c) red[wv][c] = acc[c];
    __syncthreads();
    if (tid < NCLASS) {
        float s = red[0][tid] + red[1][tid] + red[2][tid] + red[3][tid] + bias[tid];
        int b = row >> 10, t = row & (NT - 1);
        out[((size_t)b * NCLASS + tid) * NT + t] = siluf(s);
    }
}

extern "C" void kernel_launch(void* const* d_in, const int* in_sizes, int n_in,
                              void* d_out, int out_size, void* d_ws, size_t ws_size,
                              hipStream_t stream)
{
    const float* x      = (const float*)d_in[0];
    const float* c1a_w  = (const float*)d_in[1];
    const float* c1a_b  = (const float*)d_in[2];
    const float* c1b_w  = (const float*)d_in[3];
    const float* c1b_b  = (const float*)d_in[4];
    const float* c1s_w  = (const float*)d_in[5];
    const float* c1s_b  = (const float*)d_in[6];
    const float* c2a_w  = (const float*)d_in[7];
    const float* c2a_b  = (const float*)d_in[8];
    const float* c2b_w  = (const float*)d_in[9];
    const float* c2b_b  = (const float*)d_in[10];
    const float* norm_w = (const float*)d_in[11];
    const float* in_w   = (const float*)d_in[12];
    const float* conv_w = (const float*)d_in[13];
    const float* conv_b = (const float*)d_in[14];
    const float* xproj_w= (const float*)d_in[15];
    const float* dt_w   = (const float*)d_in[16];
    const float* dt_b   = (const float*)d_in[17];
    const float* A_log  = (const float*)d_in[18];
    const float* Dp     = (const float*)d_in[19];
    const float* out_w  = (const float*)d_in[20];
    const float* fc_w   = (const float*)d_in[21];
    const float* fc_b   = (const float*)d_in[22];
    float* outp = (float*)d_out;
    (void)in_sizes; (void)n_in; (void)out_size; (void)ws_size;

    float* W = (float*)d_ws;
    size_t o = 0;
    auto take = [&](size_t n) { float* p = W + o; o += n + 1024; return p; };
    float* HCAT = take((size_t)NB * NDIM * NT);          // 1.57M
    float* XZ   = take((size_t)NB * NT * 2 * DINNER);    // 50.3M  (also T1; y in u-cols)
    float* RA   = take((size_t)NB * NT * DINNER);        // 25.2M  (P1 / U)
    float* RB   = take((size_t)NB * NT * DINNER);        // 25.2M  (T3 / XPART / DELTA)
    float* P2   = take((size_t)NB * NT * DMODEL);        // 12.6M  (P2 / XN)
    float* RES  = take((size_t)NB * NT * DMODEL);        // 12.6M  residual stream
    float* XDBL = take((size_t)MROWS * 128);             // 1.0M
    float* XPART = RB;                                   // alias: T3 dead when used

    const int n1 = NB * NDIM * NT;
    k_prep  <<<(n1 + 255) / 256, 256, 0, stream>>>(x, HCAT);
    k_conv1a<<<(n1 + 255) / 256, 256, 0, stream>>>(HCAT, c1a_w, c1a_b, XZ);
    k_conv1b_pool<<<dim3(16, 96, NB), 256, 0, stream>>>(XZ, HCAT, c1b_w, c1b_b, c1s_w, c1s_b, RA);
    k_conv2a<<<dim3(16, 48, NB), 256, 0, stream>>>(RA, c2a_w, c2a_b, RB);
    k_conv2b_pool<<<dim3(16, 48, NB), 256, 0, stream>>>(RB, RA, c2b_w, c2b_b, P2);
    k_transpose<<<dim3(NT / 32, DMODEL / 32, NB), dim3(32, 8), 0, stream>>>(P2, RES);

    for (int l = 0; l < NLAYER; ++l) {
        k_rmsnorm<<<MROWS, 256, 0, stream>>>(RES, norm_w + (size_t)l * DMODEL, P2);
        k_gemm_nt<0><<<dim3(2 * DINNER / 64, MROWS / 64, 1), 256, 0, stream>>>(
            P2, DMODEL, in_w + (size_t)l * 2 * DINNER * DMODEL, DMODEL,
            XZ, 2 * DINNER, DMODEL, nullptr, 0);
        k_conv1d<<<(NB * NT * (DINNER / 4) + 255) / 256, 256, 0, stream>>>(
            XZ, conv_w + (size_t)l * DINNER * 4, conv_b + (size_t)l * DINNER, RA);
        k_gemm_nt<0><<<dim3(128 / 64, MROWS / 64, 8), 256, 0, stream>>>(
            RA, DINNER, xproj_w + (size_t)l * 128 * DINNER, DINNER,
            XPART, 128, DINNER, nullptr, (size_t)MROWS * 128);
        k_reduce8<<<(MROWS * 128 + 255) / 256, 256, 0, stream>>>(XPART, XDBL);
        k_gemm_nt<1><<<dim3(DINNER / 64, MROWS / 64, 1), 256, 0, stream>>>(
            XDBL, 128, dt_w + (size_t)l * DINNER * DTRANK, DTRANK,
            RB, DINNER, DTRANK, dt_b + (size_t)l * DINNER, 0);
        k_scan<<<dim3(DINNER / 32, NB), 256, 0, stream>>>(
            RB, RA, XZ, XDBL, A_log + (size_t)l * DINNER * DSTATE, Dp + (size_t)l * DINNER);
        k_gemm_nt<2><<<dim3(DMODEL / 64, MROWS / 64, 1), 256, 0, stream>>>(
            XZ, 2 * DINNER, out_w + (size_t)l * DMODEL * DINNER, DINNER,
            RES, DMODEL, DINNER, nullptr, 0);
    }
    k_fc<<<MROWS, 256, 0, stream>>>(RES, fc_w, fc_b, outp);
}

// Round 2
// 8661.107 us; speedup vs baseline: 2.1471x; 2.1471x over previous
//
#include <hip/hip_runtime.h>
#include <cstdint>
#include <cstddef>

#define DEV static __device__ __forceinline__

typedef unsigned short u16;
typedef unsigned int   u32;
typedef __bf16 bf16x8 __attribute__((ext_vector_type(8)));
typedef float  f32x4  __attribute__((ext_vector_type(4)));

namespace {
constexpr int NB     = 8;
constexpr int NT     = 1024;
constexpr int NMEL   = 96;
constexpr int NDIM   = 192;
constexpr int NCH    = 32;
constexpr int DMODEL = 1536;
constexpr int DINNER = 3072;
constexpr int DSTATE = 16;
constexpr int DTRANK = 96;
constexpr int NLAYER = 4;
constexpr int NCLASS = 5;
constexpr int MROWS  = NB * NT;   // 8192
}

DEV float siluf(float x)    { return x / (1.0f + __expf(-x)); }
DEV float softplusf(float x){ return fmaxf(x, 0.0f) + log1pf(__expf(-fabsf(x))); }

DEV u16 f2bf(float f) {
    u32 u = __float_as_uint(f);
    u32 r = u + 0x7FFFu + ((u >> 16) & 1u);
    return (u16)(r >> 16);
}
DEV float bf2f(u16 h) { return __uint_as_float(((u32)h) << 16); }

#define GLD(gp, lp) __builtin_amdgcn_global_load_lds( \
    (const __attribute__((address_space(1))) u32*)(const void*)(gp), \
    (__attribute__((address_space(3))) u32*)(void*)(lp), 16, 0, 0)

// ---------------- prep: x -> hcat (B,192,T): [x ; relu(diff)] ----------------
__global__ __launch_bounds__(256) void k_prep(const float* __restrict__ x,
                                              float* __restrict__ hcat)
{
    int idx = blockIdx.x * 256 + threadIdx.x;
    if (idx >= NB * NDIM * NT) return;
    int t = idx & (NT - 1);
    int m = (idx >> 10) % NDIM;
    int b = idx / (NDIM * NT);
    float v;
    if (m < NMEL) {
        v = x[((size_t)b * NMEL + m) * NT + t];
    } else {
        int mm = m - NMEL;
        v = 0.f;
        if (t > 0) {
            const float* p = x + ((size_t)b * NMEL + mm) * NT + t;
            v = fmaxf(p[0] - p[-1], 0.f);
        }
    }
    hcat[idx] = v;
}

// ---------------- conv1a (1->32, 3x3) + silu ----------------
__global__ __launch_bounds__(256) void k_conv1a(const float* __restrict__ hcat,
    const float* __restrict__ w, const float* __restrict__ bias,
    float* __restrict__ out)   // (B,32,192,T)
{
    int idx = blockIdx.x * 256 + threadIdx.x;
    if (idx >= NB * NDIM * NT) return;
    int t = idx & (NT - 1);
    int h = (idx >> 10) % NDIM;
    int b = idx / (NDIM * NT);
    float in[3][3];
    #pragma unroll
    for (int dh = 0; dh < 3; ++dh)
        #pragma unroll
        for (int dw = 0; dw < 3; ++dw) {
            int hh = h + dh - 1, tt = t + dw - 1;
            in[dh][dw] = (hh >= 0 && hh < NDIM && tt >= 0 && tt < NT)
                       ? hcat[((size_t)b * NDIM + hh) * NT + tt] : 0.f;
        }
    for (int c = 0; c < NCH; ++c) {
        float acc = bias[c];
        #pragma unroll
        for (int dh = 0; dh < 3; ++dh)
            #pragma unroll
            for (int dw = 0; dw < 3; ++dw)
                acc = fmaf(in[dh][dw], w[c * 9 + dh * 3 + dw], acc);
        out[(((size_t)b * NCH + c) * NDIM + h) * NT + t] = siluf(acc);
    }
}

// ------- conv1b (32->32 3x3) + 1x1-skip(hcat) + silu + maxpool(2,1) -------
__global__ __launch_bounds__(256) void k_conv1b_pool(
    const float* __restrict__ t1, const float* __restrict__ hcat,
    const float* __restrict__ w, const float* __restrict__ bias,
    const float* __restrict__ sw, const float* __restrict__ sb,
    float* __restrict__ out)   // (B,32,96,T)
{
    __shared__ float sT[NCH][4][66];
    const int w0 = blockIdx.x * 64;
    const int ho = blockIdx.y;
    const int b  = blockIdx.z;
    const int tid = threadIdx.x;
    for (int e = tid; e < NCH * 4 * 66; e += 256) {
        int wc = e % 66;
        int r  = e / 66;
        int hr = r & 3;
        int ci = r >> 2;
        int h  = 2 * ho - 1 + hr;
        int tt = w0 - 1 + wc;
        float v = 0.f;
        if (h >= 0 && h < NDIM && tt >= 0 && tt < NT)
            v = t1[(((size_t)b * NCH + ci) * NDIM + h) * NT + tt];
        sT[ci][hr][wc] = v;
    }
    __syncthreads();
    const int wl   = tid & 63;
    const int slot = tid >> 6;
    float acc0[8], acc1[8];
    #pragma unroll
    for (int j = 0; j < 8; ++j) { acc0[j] = bias[slot * 8 + j]; acc1[j] = acc0[j]; }
    for (int ci = 0; ci < NCH; ++ci) {
        #pragma unroll
        for (int dh = 0; dh < 3; ++dh) {
            #pragma unroll
            for (int dw = 0; dw < 3; ++dw) {
                float v0 = sT[ci][dh    ][wl + dw];
                float v1 = sT[ci][dh + 1][wl + dw];
                #pragma unroll
                for (int j = 0; j < 8; ++j) {
                    float wg = w[((slot * 8 + j) * NCH + ci) * 9 + dh * 3 + dw];
                    acc0[j] = fmaf(v0, wg, acc0[j]);
                    acc1[j] = fmaf(v1, wg, acc1[j]);
                }
            }
        }
    }
    float hc0 = hcat[((size_t)b * NDIM + 2 * ho    ) * NT + w0 + wl];
    float hc1 = hcat[((size_t)b * NDIM + 2 * ho + 1) * NT + w0 + wl];
    #pragma unroll
    for (int j = 0; j < 8; ++j) {
        int c = slot * 8 + j;
        float r0 = siluf(acc0[j] + fmaf(hc0, sw[c], sb[c]));
        float r1 = siluf(acc1[j] + fmaf(hc1, sw[c], sb[c]));
        out[(((size_t)b * NCH + c) * NMEL + ho) * NT + w0 + wl] = fmaxf(r0, r1);
    }
}

// ---------------- conv2a (32->32 3x3) + silu ----------------
__global__ __launch_bounds__(256) void k_conv2a(
    const float* __restrict__ p1, const float* __restrict__ w,
    const float* __restrict__ bias, float* __restrict__ out)  // (B,32,96,T)
{
    __shared__ float sT[NCH][4][66];
    const int w0 = blockIdx.x * 64;
    const int ht = blockIdx.y;
    const int b  = blockIdx.z;
    const int tid = threadIdx.x;
    for (int e = tid; e < NCH * 4 * 66; e += 256) {
        int wc = e % 66;
        int r  = e / 66;
        int hr = r & 3;
        int ci = r >> 2;
        int h  = 2 * ht - 1 + hr;
        int tt = w0 - 1 + wc;
        float v = 0.f;
        if (h >= 0 && h < NMEL && tt >= 0 && tt < NT)
            v = p1[(((size_t)b * NCH + ci) * NMEL + h) * NT + tt];
        sT[ci][hr][wc] = v;
    }
    __syncthreads();
    const int wl   = tid & 63;
    const int slot = tid >> 6;
    float acc0[8], acc1[8];
    #pragma unroll
    for (int j = 0; j < 8; ++j) { acc0[j] = bias[slot * 8 + j]; acc1[j] = acc0[j]; }
    for (int ci = 0; ci < NCH; ++ci) {
        #pragma unroll
        for (int dh = 0; dh < 3; ++dh) {
            #pragma unroll
            for (int dw = 0; dw < 3; ++dw) {
                float v0 = sT[ci][dh    ][wl + dw];
                float v1 = sT[ci][dh + 1][wl + dw];
                #pragma unroll
                for (int j = 0; j < 8; ++j) {
                    float wg = w[((slot * 8 + j) * NCH + ci) * 9 + dh * 3 + dw];
                    acc0[j] = fmaf(v0, wg, acc0[j]);
                    acc1[j] = fmaf(v1, wg, acc1[j]);
                }
            }
        }
    }
    #pragma unroll
    for (int j = 0; j < 8; ++j) {
        int c = slot * 8 + j;
        out[(((size_t)b * NCH + c) * NMEL + 2 * ht    ) * NT + w0 + wl] = siluf(acc0[j]);
        out[(((size_t)b * NCH + c) * NMEL + 2 * ht + 1) * NT + w0 + wl] = siluf(acc1[j]);
    }
}

// ------- conv2b (32->32 3x3) + identity-skip + silu + maxpool -------
__global__ __launch_bounds__(256) void k_conv2b_pool(
    const float* __restrict__ t3, const float* __restrict__ p1,
    const float* __restrict__ w, const float* __restrict__ bias,
    float* __restrict__ out)   // (B,32,48,T)
{
    __shared__ float sT[NCH][4][66];
    const int w0 = blockIdx.x * 64;
    const int ho = blockIdx.y;
    const int b  = blockIdx.z;
    const int tid = threadIdx.x;
    for (int e = tid; e < NCH * 4 * 66; e += 256) {
        int wc = e % 66;
        int r  = e / 66;
        int hr = r & 3;
        int ci = r >> 2;
        int h  = 2 * ho - 1 + hr;
        int tt = w0 - 1 + wc;
        float v = 0.f;
        if (h >= 0 && h < NMEL && tt >= 0 && tt < NT)
            v = t3[(((size_t)b * NCH + ci) * NMEL + h) * NT + tt];
        sT[ci][hr][wc] = v;
    }
    __syncthreads();
    const int wl   = tid & 63;
    const int slot = tid >> 6;
    float acc0[8], acc1[8];
    #pragma unroll
    for (int j = 0; j < 8; ++j) { acc0[j] = bias[slot * 8 + j]; acc1[j] = acc0[j]; }
    for (int ci = 0; ci < NCH; ++ci) {
        #pragma unroll
        for (int dh = 0; dh < 3; ++dh) {
            #pragma unroll
            for (int dw = 0; dw < 3; ++dw) {
                float v0 = sT[ci][dh    ][wl + dw];
                float v1 = sT[ci][dh + 1][wl + dw];
                #pragma unroll
                for (int j = 0; j < 8; ++j) {
                    float wg = w[((slot * 8 + j) * NCH + ci) * 9 + dh * 3 + dw];
                    acc0[j] = fmaf(v0, wg, acc0[j]);
                    acc1[j] = fmaf(v1, wg, acc1[j]);
                }
            }
        }
    }
    #pragma unroll
    for (int j = 0; j < 8; ++j) {
        int c = slot * 8 + j;
        float sk0 = p1[(((size_t)b * NCH + c) * NMEL + 2 * ho    ) * NT + w0 + wl];
        float sk1 = p1[(((size_t)b * NCH + c) * NMEL + 2 * ho + 1) * NT + w0 + wl];
        float r0 = siluf(acc0[j] + sk0);
        float r1 = siluf(acc1[j] + sk1);
        out[(((size_t)b * NCH + c) * 48 + ho) * NT + w0 + wl] = fmaxf(r0, r1);
    }
}

// ---------------- transpose (B,1536,1024) -> (B,1024,1536) ----------------
__global__ __launch_bounds__(256) void k_transpose(const float* __restrict__ in,
                                                   float* __restrict__ out)
{
    __shared__ float tile[32][33];
    int t0 = blockIdx.x * 32;
    int d0 = blockIdx.y * 32;
    int b  = blockIdx.z;
    int tx = threadIdx.x;
    int ty = threadIdx.y;
    #pragma unroll
    for (int j = 0; j < 4; ++j)
        tile[ty + j * 8][tx] = in[((size_t)b * DMODEL + d0 + ty + j * 8) * NT + t0 + tx];
    __syncthreads();
    #pragma unroll
    for (int j = 0; j < 4; ++j)
        out[((size_t)b * NT + t0 + ty + j * 8) * DMODEL + d0 + tx] = tile[tx][ty + j * 8];
}

// ---------------- rmsnorm over D_MODEL -> bf16 hi/lo planes ----------------
__global__ __launch_bounds__(256) void k_rmsnorm(const float* __restrict__ in,
    const float* __restrict__ w, u16* __restrict__ oh, u16* __restrict__ ol)
{
    int row = blockIdx.x;
    int tid = threadIdx.x;
    const float* p = in + (size_t)row * DMODEL;
    float v[6]; float ss = 0.f;
    #pragma unroll
    for (int j = 0; j < 6; ++j) { v[j] = p[tid + j * 256]; ss = fmaf(v[j], v[j], ss); }
    #pragma unroll
    for (int off = 1; off < 64; off <<= 1) ss += __shfl_xor(ss, off);
    __shared__ float red[4];
    int lane = tid & 63, wv = tid >> 6;
    if (lane == 0) red[wv] = ss;
    __syncthreads();
    float tot = red[0] + red[1] + red[2] + red[3];
    float sc = rsqrtf(tot * (1.0f / DMODEL) + 1e-5f);
    #pragma unroll
    for (int j = 0; j < 6; ++j) {
        int col = tid + j * 256;
        float xv = v[j] * sc * w[col];
        u16 h = f2bf(xv);
        oh[(size_t)row * DMODEL + col] = h;
        ol[(size_t)row * DMODEL + col] = f2bf(xv - bf2f(h));
    }
}

// ---------------- split fp32 -> bf16 hi/lo (n divisible by 4) ----------------
__global__ __launch_bounds__(256) void k_split(const float* __restrict__ src,
    u16* __restrict__ dh, u16* __restrict__ dl, int n4)
{
    int idx = blockIdx.x * 256 + threadIdx.x;
    if (idx >= n4) return;
    float4 v = ((const float4*)src)[idx];
    u16 h0 = f2bf(v.x), h1 = f2bf(v.y), h2 = f2bf(v.z), h3 = f2bf(v.w);
    u16 l0 = f2bf(v.x - bf2f(h0)), l1 = f2bf(v.y - bf2f(h1));
    u16 l2 = f2bf(v.z - bf2f(h2)), l3 = f2bf(v.w - bf2f(h3));
    uint2 hv = { (u32)h0 | ((u32)h1 << 16), (u32)h2 | ((u32)h3 << 16) };
    uint2 lv = { (u32)l0 | ((u32)l1 << 16), (u32)l2 | ((u32)l3 << 16) };
    ((uint2*)dh)[idx] = hv;
    ((uint2*)dl)[idx] = lv;
}

// ---------------- split dt_w [3072][96] -> padded [3072][128] hi/lo ----------------
__global__ __launch_bounds__(256) void k_wsplit_pad(const float* __restrict__ src,
    u16* __restrict__ dh, u16* __restrict__ dl)
{
    int idx = blockIdx.x * 256 + threadIdx.x;
    if (idx >= DINNER * 128) return;
    int col = idx & 127, row = idx >> 7;
    float v = (col < DTRANK) ? src[(size_t)row * DTRANK + col] : 0.f;
    u16 h = f2bf(v);
    dh[idx] = h;
    dl[idx] = f2bf(v - bf2f(h));
}

// ---------------- MFMA GEMM: C[M,N] = A[M,K] * B[N,K]^T, 3-product bf16 ----------------
// A,B given as hi/lo bf16 planes (u16). EPI: 0 store (+zStride slab), 1 softplus(acc+bias), 2 C += acc
template<int EPI>
__global__ __launch_bounds__(256) void k_gemm_mfma(
    const u16* __restrict__ Ahi, const u16* __restrict__ Alo, int lda,
    const u16* __restrict__ Bhi, const u16* __restrict__ Blo, int ldb,
    float* __restrict__ C, int ldc, int Ktot,
    const float* __restrict__ bias, size_t zStride)
{
    __shared__ __align__(16) u16 lds[4][8192];   // planes: Ahi, Alo, Bhi, Blo (64 KiB)
    const int tid = threadIdx.x;
    const int m0 = blockIdx.y * 128, n0 = blockIdx.x * 128;
    const int kPer = Ktot / gridDim.z;
    const int kBase = blockIdx.z * kPer;
    const int wid = tid >> 6, lane = tid & 63;
    const int wr = wid >> 1, wc = wid & 1;
    const int fr = lane & 15, fq = lane >> 4;
    // staging addressing: dest linear; source slot pre-swizzled (rule #21)
    const int srow  = tid >> 3;                       // 0..31 per instruction
    const int sslot = (tid & 7) ^ ((tid >> 3) & 7);

    f32x4 acc[4][4];
    #pragma unroll
    for (int mi = 0; mi < 4; ++mi)
        #pragma unroll
        for (int ni = 0; ni < 4; ++ni) acc[mi][ni] = (f32x4){0.f, 0.f, 0.f, 0.f};

    for (int k0 = kBase; k0 < kBase + kPer; k0 += 64) {
        #pragma unroll
        for (int i = 0; i < 4; ++i) {
            int row = i * 32 + srow;
            size_t offA = (size_t)(m0 + row) * lda + k0 + sslot * 8;
            size_t offB = (size_t)(n0 + row) * ldb + k0 + sslot * 8;
            u16* lb = &lds[0][0] + i * 2048 + (wid << 9);
            GLD(Ahi + offA, lb);
            GLD(Alo + offA, lb + 8192);
            GLD(Bhi + offB, lb + 16384);
            GLD(Blo + offB, lb + 24576);
        }
        __syncthreads();
        #pragma unroll
        for (int h = 0; h < 2; ++h) {
            bf16x8 ah[4], al[4], bh[4], bl[4];
            #pragma unroll
            for (int mi = 0; mi < 4; ++mi) {
                int row = wr * 64 + mi * 16 + fr;
                int sl  = (h * 4 + fq) ^ (row & 7);
                const u16* p = &lds[0][row * 64 + sl * 8];
                ah[mi] = *(const bf16x8*)p;
                al[mi] = *(const bf16x8*)(p + 8192);
            }
            #pragma unroll
            for (int ni = 0; ni < 4; ++ni) {
                int row = wc * 64 + ni * 16 + fr;
                int sl  = (h * 4 + fq) ^ (row & 7);
                const u16* p = &lds[2][row * 64 + sl * 8];
                bh[ni] = *(const bf16x8*)p;
                bl[ni] = *(const bf16x8*)(p + 8192);
            }
            #pragma unroll
            for (int mi = 0; mi < 4; ++mi)
                #pragma unroll
                for (int ni = 0; ni < 4; ++ni) {
                    acc[mi][ni] = __builtin_amdgcn_mfma_f32_16x16x32_bf16(ah[mi], bh[ni], acc[mi][ni], 0, 0, 0);
                    acc[mi][ni] = __builtin_amdgcn_mfma_f32_16x16x32_bf16(ah[mi], bl[ni], acc[mi][ni], 0, 0, 0);
                    acc[mi][ni] = __builtin_amdgcn_mfma_f32_16x16x32_bf16(al[mi], bh[ni], acc[mi][ni], 0, 0, 0);
                }
        }
        __syncthreads();
    }

    float* Cz = C + (EPI == 0 ? (size_t)blockIdx.z * zStride : (size_t)0);
    #pragma unroll
    for (int mi = 0; mi < 4; ++mi)
        #pragma unroll
        for (int ni = 0; ni < 4; ++ni) {
            int gr = m0 + wr * 64 + mi * 16 + fq * 4;
            int gc = n0 + wc * 64 + ni * 16 + fr;
            float* cp = Cz + (size_t)gr * ldc + gc;
            #pragma unroll
            for (int r = 0; r < 4; ++r) {
                float v = acc[mi][ni][r];
                if (EPI == 1) v = softplusf(v + bias[gc]);
                if (EPI == 2) v += cp[(size_t)r * ldc];
                cp[(size_t)r * ldc] = v;
            }
        }
}

// ---------------- depthwise causal conv1d(k=4)+bias+silu -> u hi/lo ----------------
__global__ __launch_bounds__(256) void k_conv1d(
    const float* __restrict__ xz, const float* __restrict__ w,
    const float* __restrict__ bias, u16* __restrict__ uh, u16* __restrict__ ul)
{
    int idx = blockIdx.x * 256 + threadIdx.x;
    if (idx >= NB * NT * (DINNER / 4)) return;
    int dv = idx % (DINNER / 4);
    int t  = (idx / (DINNER / 4)) % NT;
    int b  = idx / ((DINNER / 4) * NT);
    int d  = dv * 4;
    const float* base = xz + ((size_t)b * NT + t) * (2 * DINNER) + d;
    float4 a[4];
    #pragma unroll
    for (int k = 0; k < 4; ++k) {
        int tm = t - 3 + k;
        if (tm >= 0) a[k] = *(const float4*)(base + (ptrdiff_t)(k - 3) * (2 * DINNER));
        else         a[k] = make_float4(0.f, 0.f, 0.f, 0.f);
    }
    float4 w0 = *(const float4*)(w + (size_t)(d + 0) * 4);
    float4 w1 = *(const float4*)(w + (size_t)(d + 1) * 4);
    float4 w2 = *(const float4*)(w + (size_t)(d + 2) * 4);
    float4 w3 = *(const float4*)(w + (size_t)(d + 3) * 4);
    float4 bb = *(const float4*)(bias + d);
    float o0 = siluf(bb.x + a[0].x * w0.x + a[1].x * w0.y + a[2].x * w0.z + a[3].x * w0.w);
    float o1 = siluf(bb.y + a[0].y * w1.x + a[1].y * w1.y + a[2].y * w1.z + a[3].y * w1.w);
    float o2 = siluf(bb.z + a[0].z * w2.x + a[1].z * w2.y + a[2].z * w2.z + a[3].z * w2.w);
    float o3 = siluf(bb.w + a[0].w * w3.x + a[1].w * w3.y + a[2].w * w3.z + a[3].w * w3.w);
    u16 h0 = f2bf(o0), h1 = f2bf(o1), h2 = f2bf(o2), h3 = f2bf(o3);
    u16 l0 = f2bf(o0 - bf2f(h0)), l1 = f2bf(o1 - bf2f(h1));
    u16 l2 = f2bf(o2 - bf2f(h2)), l3 = f2bf(o3 - bf2f(h3));
    size_t ob = ((size_t)b * NT + t) * DINNER + d;
    uint2 hv = { (u32)h0 | ((u32)h1 << 16), (u32)h2 | ((u32)h3 << 16) };
    uint2 lv = { (u32)l0 | ((u32)l1 << 16), (u32)l2 | ((u32)l3 << 16) };
    *(uint2*)(uh + ob) = hv;
    *(uint2*)(ul + ob) = lv;
}

// ---------------- reduce 4 split-K slabs of x_proj ----------------
__global__ __launch_bounds__(256) void k_reduce4(const float* __restrict__ part,
                                                 float* __restrict__ out)
{
    int idx = blockIdx.x * 256 + threadIdx.x;
    if (idx >= MROWS * 128) return;
    float s = part[idx] + part[(size_t)1 * MROWS * 128 + idx]
            + part[(size_t)2 * MROWS * 128 + idx] + part[(size_t)3 * MROWS * 128 + idx];
    out[idx] = s;
}

// ---------------- selective scan + gating -> y hi/lo (in place over u planes) ----------------
__global__ __launch_bounds__(256) void k_scan(
    const float* __restrict__ xz,          // delta in u-cols, z in z-cols
    u16* uh, u16* ul,                      // u in, y out (aliased)
    const float* __restrict__ xdbl,
    const float* __restrict__ A_log, const float* __restrict__ Dp)
{
    const int tid = threadIdx.x;
    const int g = tid >> 3;
    const int i = tid & 7;
    const int d = blockIdx.x * 32 + g;
    const int b = blockIdx.y;
    const float L2E = 1.44269504088896340736f;
    float aa0 = -__expf(A_log[d * DSTATE + 2 * i    ]) * L2E;
    float aa1 = -__expf(A_log[d * DSTATE + 2 * i + 1]) * L2E;
    const float dp = Dp[d];
    const float* dP = xz + (size_t)b * NT * (2 * DINNER) + d;
    const float* zP = dP + DINNER;
    const u16* uhP = uh + (size_t)b * NT * DINNER + d;
    const u16* ulP = ul + (size_t)b * NT * DINNER + d;
    u16* yhP = (u16*)uhP;
    u16* ylP = (u16*)ulP;
    const float* bP = xdbl + (size_t)b * NT * 128 + DTRANK + 2 * i;
    const float* cP = bP + DSTATE;
    float h0 = 0.f, h1 = 0.f;
    float dlt = dP[0], zz = zP[0];
    float uu = bf2f(uhP[0]) + bf2f(ulP[0]);
    float2 Bf = *(const float2*)bP;
    float2 Cf = *(const float2*)cP;
    for (int t = 0; t < NT; ++t) {
        float dlt_n = 0.f, uu_n = 0.f, zz_n = 0.f;
        float2 Bn = {0.f, 0.f}, Cn = {0.f, 0.f};
        if (t + 1 < NT) {
            dlt_n = dP[2 * DINNER]; zz_n = zP[2 * DINNER];
            uu_n = bf2f(uhP[DINNER]) + bf2f(ulP[DINNER]);
            Bn = *(const float2*)(bP + 128); Cn = *(const float2*)(cP + 128);
        }
        float du = dlt * uu;
        h0 = fmaf(exp2f(dlt * aa0), h0, du * Bf.x);
        h1 = fmaf(exp2f(dlt * aa1), h1, du * Bf.y);
        float p = fmaf(h0, Cf.x, h1 * Cf.y);
        p += __shfl_xor(p, 1);
        p += __shfl_xor(p, 2);
        p += __shfl_xor(p, 4);
        if (i == 0) {
            float yv = (p + uu * dp) * siluf(zz);
            u16 hh = f2bf(yv);
            yhP[0] = hh;
            ylP[0] = f2bf(yv - bf2f(hh));
        }
        dP += 2 * DINNER; zP += 2 * DINNER;
        uhP += DINNER; ulP += DINNER; yhP += DINNER; ylP += DINNER;
        bP += 128; cP += 128;
        dlt = dlt_n; zz = zz_n; uu = uu_n; Bf = Bn; Cf = Cn;
    }
}

// ---------------- final fc + silu + transpose to (B,5,T) ----------------
__global__ __launch_bounds__(256) void k_fc(const float* __restrict__ hR,
    const float* __restrict__ w, const float* __restrict__ bias,
    float* __restrict__ out)
{
    int row = blockIdx.x;
    int tid = threadIdx.x;
    const float* p = hR + (size_t)row * DMODEL;
    float acc[NCLASS] = {0.f, 0.f, 0.f, 0.f, 0.f};
    #pragma unroll
    for (int j = 0; j < 6; ++j) {
        int col = tid + j * 256;
        float v = p[col];
        #pragma unroll
        for (int c = 0; c < NCLASS; ++c)
            acc[c] = fmaf(v, w[c * DMODEL + col], acc[c]);
    }
    #pragma unroll
    for (int c = 0; c < NCLASS; ++c)
        #pragma unroll
        for (int off = 1; off < 64; off <<= 1)
            acc[c] += __shfl_xor(acc[c], off);
    __shared__ float red[4][NCLASS];
    int lane = tid & 63, wv = tid >> 6;
    if (lane == 0)
        for (int c = 0; c < NCLASS; ++c) red[wv][c] = acc[c];
    __syncthreads();
    if (tid < NCLASS) {
        float s = red[0][tid] + red[1][tid] + red[2][tid] + red[3][tid] + bias[tid];
        int b = row >> 10, t = row & (NT - 1);
        out[((size_t)b * NCLASS + tid) * NT + t] = siluf(s);
    }
}

extern "C" void kernel_launch(void* const* d_in, const int* in_sizes, int n_in,
                              void* d_out, int out_size, void* d_ws, size_t ws_size,
                              hipStream_t stream)
{
    const float* x      = (const float*)d_in[0];
    const float* c1a_w  = (const float*)d_in[1];
    const float* c1a_b  = (const float*)d_in[2];
    const float* c1b_w  = (const float*)d_in[3];
    const float* c1b_b  = (const float*)d_in[4];
    const float* c1s_w  = (const float*)d_in[5];
    const float* c1s_b  = (const float*)d_in[6];
    const float* c2a_w  = (const float*)d_in[7];
    const float* c2a_b  = (const float*)d_in[8];
    const float* c2b_w  = (const float*)d_in[9];
    const float* c2b_b  = (const float*)d_in[10];
    const float* norm_w = (const float*)d_in[11];
    const float* in_w   = (const float*)d_in[12];
    const float* conv_w = (const float*)d_in[13];
    const float* conv_b = (const float*)d_in[14];
    const float* xproj_w= (const float*)d_in[15];
    const float* dt_w   = (const float*)d_in[16];
    const float* dt_b   = (const float*)d_in[17];
    const float* A_log  = (const float*)d_in[18];
    const float* Dp     = (const float*)d_in[19];
    const float* out_w  = (const float*)d_in[20];
    const float* fc_w   = (const float*)d_in[21];
    const float* fc_b   = (const float*)d_in[22];
    float* outp = (float*)d_out;
    (void)in_sizes; (void)n_in; (void)out_size; (void)ws_size;

    char* base = (char*)d_ws;
    size_t off = 0;
    auto takeB = [&](size_t bytes) { void* p = base + off; off = (off + bytes + 255) & ~(size_t)255; return p; };
    float* HCAT = (float*)takeB((size_t)NB * NDIM * NT * 4);          // 6.3 MB
    float* XZ   = (float*)takeB((size_t)MROWS * 2 * DINNER * 4);      // 201 MB (T1/T3; xz; delta in u-cols)
    float* RES  = (float*)takeB((size_t)MROWS * DMODEL * 4);          // 50 MB
    u16*   XNh  = (u16*)takeB((size_t)MROWS * DMODEL * 2);            // 25 MB (P2 aliases XNh..XNl)
    u16*   XNl  = (u16*)takeB((size_t)MROWS * DMODEL * 2);            // 25 MB
    u16*   Uh   = (u16*)takeB((size_t)MROWS * DINNER * 2);            // 50 MB (P1 aliases Uh..Ul; y in place)
    u16*   Ul   = (u16*)takeB((size_t)MROWS * DINNER * 2);            // 50 MB
    float* XDBL = (float*)takeB((size_t)MROWS * 128 * 4);             // 4.2 MB
    float* XPART= (float*)takeB((size_t)4 * MROWS * 128 * 4);         // 16.8 MB
    u16*   XDh  = (u16*)takeB((size_t)MROWS * 128 * 2);               // 2.1 MB
    u16*   XDl  = (u16*)takeB((size_t)MROWS * 128 * 2);               // 2.1 MB
    u16*   Wh   = (u16*)takeB((size_t)9437184 * 2);                   // 18.9 MB
    u16*   Wl   = (u16*)takeB((size_t)9437184 * 2);                   // 18.9 MB
    float* P1 = (float*)Uh;     // 25.2M f32 spans Uh..Ul
    float* P2 = (float*)XNh;    // 12.6M f32 spans XNh..XNl

    const int n1 = NB * NDIM * NT;
    k_prep  <<<(n1 + 255) / 256, 256, 0, stream>>>(x, HCAT);
    k_conv1a<<<(n1 + 255) / 256, 256, 0, stream>>>(HCAT, c1a_w, c1a_b, XZ);
    k_conv1b_pool<<<dim3(16, 96, NB), 256, 0, stream>>>(XZ, HCAT, c1b_w, c1b_b, c1s_w, c1s_b, P1);
    k_conv2a<<<dim3(16, 48, NB), 256, 0, stream>>>(P1, c2a_w, c2a_b, XZ);
    k_conv2b_pool<<<dim3(16, 48, NB), 256, 0, stream>>>(XZ, P1, c2b_w, c2b_b, P2);
    k_transpose<<<dim3(NT / 32, DMODEL / 32, NB), dim3(32, 8), 0, stream>>>(P2, RES);

    for (int l = 0; l < NLAYER; ++l) {
        k_rmsnorm<<<MROWS, 256, 0, stream>>>(RES, norm_w + (size_t)l * DMODEL, XNh, XNl);
        k_split<<<(9437184 / 4 + 255) / 256, 256, 0, stream>>>(
            in_w + (size_t)l * 2 * DINNER * DMODEL, Wh, Wl, 9437184 / 4);
        k_gemm_mfma<0><<<dim3(2 * DINNER / 128, MROWS / 128, 1), 256, 0, stream>>>(
            XNh, XNl, DMODEL, Wh, Wl, DMODEL, XZ, 2 * DINNER, DMODEL, nullptr, 0);
        k_conv1d<<<(NB * NT * (DINNER / 4) + 255) / 256, 256, 0, stream>>>(
            XZ, conv_w + (size_t)l * DINNER * 4, conv_b + (size_t)l * DINNER, Uh, Ul);
        k_split<<<(393216 / 4 + 255) / 256, 256, 0, stream>>>(
            xproj_w + (size_t)l * 128 * DINNER, Wh, Wl, 393216 / 4);
        k_gemm_mfma<0><<<dim3(1, MROWS / 128, 4), 256, 0, stream>>>(
            Uh, Ul, DINNER, Wh, Wl, DINNER, XPART, 128, DINNER, nullptr, (size_t)MROWS * 128);
        k_reduce4<<<(MROWS * 128 + 255) / 256, 256, 0, stream>>>(XPART, XDBL);
        k_split<<<(MROWS * 128 / 4 + 255) / 256, 256, 0, stream>>>(XDBL, XDh, XDl, MROWS * 128 / 4);
        k_wsplit_pad<<<(DINNER * 128 + 255) / 256, 256, 0, stream>>>(
            dt_w + (size_t)l * DINNER * DTRANK, Wh, Wl);
        k_gemm_mfma<1><<<dim3(DINNER / 128, MROWS / 128, 1), 256, 0, stream>>>(
            XDh, XDl, 128, Wh, Wl, 128, XZ /*delta into u-cols*/, 2 * DINNER, 128,
            dt_b + (size_t)l * DINNER, 0);
        k_scan<<<dim3(DINNER / 32, NB), 256, 0, stream>>>(
            XZ, Uh, Ul, XDBL, A_log + (size_t)l * DINNER * DSTATE, Dp + (size_t)l * DINNER);
        k_split<<<(4718592 / 4 + 255) / 256, 256, 0, stream>>>(
            out_w + (size_t)l * DMODEL * DINNER, Wh, Wl, 4718592 / 4);
        k_gemm_mfma<2><<<dim3(DMODEL / 128, MROWS / 128, 1), 256, 0, stream>>>(
            Uh, Ul, DINNER, Wh, Wl, DINNER, RES, DMODEL, DINNER, nullptr, 0);
    }
    k_fc<<<MROWS, 256, 0, stream>>>(RES, fc_w, fc_b, outp);
}

// Round 3
// 7089.181 us; speedup vs baseline: 2.6231x; 1.2217x over previous
//
#include <hip/hip_runtime.h>
#include <cstdint>
#include <cstddef>

#define DEV static __device__ __forceinline__

typedef unsigned short u16;
typedef unsigned int   u32;
typedef __bf16 bf16x8 __attribute__((ext_vector_type(8)));
typedef float  f32x4  __attribute__((ext_vector_type(4)));

namespace {
constexpr int NB     = 8;
constexpr int NT     = 1024;
constexpr int NMEL   = 96;
constexpr int NDIM   = 192;
constexpr int NCH    = 32;
constexpr int DMODEL = 1536;
constexpr int DINNER = 3072;
constexpr int DSTATE = 16;
constexpr int DTRANK = 96;
constexpr int NLAYER = 4;
constexpr int NCLASS = 5;
constexpr int MROWS  = NB * NT;   // 8192
}

DEV float siluf(float x)    { return x / (1.0f + __expf(-x)); }
DEV float softplusf(float x){ return fmaxf(x, 0.0f) + log1pf(__expf(-fabsf(x))); }

DEV u16 f2bf(float f) {
    u32 u = __float_as_uint(f);
    u32 r = u + 0x7FFFu + ((u >> 16) & 1u);
    return (u16)(r >> 16);
}
DEV float bf2f(u16 h) { return __uint_as_float(((u32)h) << 16); }

#define GLD(gp, lp) __builtin_amdgcn_global_load_lds( \
    (const __attribute__((address_space(1))) u32*)(const void*)(gp), \
    (__attribute__((address_space(3))) u32*)(void*)(lp), 16, 0, 0)

// ---------------- zero pad buffer ----------------
__global__ void k_zero(u16* p) { p[threadIdx.x] = 0; }

// ---------------- prep: x -> hcat (B,192,T): [x ; relu(diff)] ----------------
__global__ __launch_bounds__(256) void k_prep(const float* __restrict__ x,
                                              float* __restrict__ hcat)
{
    int idx = blockIdx.x * 256 + threadIdx.x;
    if (idx >= NB * NDIM * NT) return;
    int t = idx & (NT - 1);
    int m = (idx >> 10) % NDIM;
    int b = idx / (NDIM * NT);
    float v;
    if (m < NMEL) {
        v = x[((size_t)b * NMEL + m) * NT + t];
    } else {
        int mm = m - NMEL;
        v = 0.f;
        if (t > 0) {
            const float* p = x + ((size_t)b * NMEL + mm) * NT + t;
            v = fmaxf(p[0] - p[-1], 0.f);
        }
    }
    hcat[idx] = v;
}

// ---------------- conv weight prep: (32,32,3,3) -> [tap][cout][ci] hi/lo ----------------
__global__ __launch_bounds__(256) void k_wconv(const float* __restrict__ w,
    u16* __restrict__ dh, u16* __restrict__ dl)
{
    int idx = blockIdx.x * 256 + threadIdx.x;
    if (idx >= 9216) return;
    int ci = idx & 31, cout = (idx >> 5) & 31, tap = idx >> 10;
    float v = w[((size_t)cout * 32 + ci) * 9 + tap];
    u16 h = f2bf(v);
    dh[idx] = h;
    dl[idx] = f2bf(v - bf2f(h));
}

// ---------------- conv1a (1->32, 3x3) + silu -> NHWC bf16 hi/lo ----------------
__global__ __launch_bounds__(256) void k_conv1a(const float* __restrict__ hcat,
    const float* __restrict__ w, const float* __restrict__ bias,
    u16* __restrict__ oh, u16* __restrict__ ol)   // (B,192,T,32)
{
    int idx = blockIdx.x * 256 + threadIdx.x;
    if (idx >= NB * NDIM * NT) return;
    int t = idx & (NT - 1);
    int h = (idx >> 10) % NDIM;
    int b = idx / (NDIM * NT);
    float in[3][3];
    #pragma unroll
    for (int dh = 0; dh < 3; ++dh)
        #pragma unroll
        for (int dw = 0; dw < 3; ++dw) {
            int hh = h + dh - 1, tt = t + dw - 1;
            in[dh][dw] = (hh >= 0 && hh < NDIM && tt >= 0 && tt < NT)
                       ? hcat[((size_t)b * NDIM + hh) * NT + tt] : 0.f;
        }
    u16 hb[32], lb[32];
    #pragma unroll
    for (int c = 0; c < NCH; ++c) {
        float acc = bias[c];
        #pragma unroll
        for (int dh = 0; dh < 3; ++dh)
            #pragma unroll
            for (int dw = 0; dw < 3; ++dw)
                acc = fmaf(in[dh][dw], w[c * 9 + dh * 3 + dw], acc);
        float o = siluf(acc);
        u16 hh2 = f2bf(o);
        hb[c] = hh2;
        lb[c] = f2bf(o - bf2f(hh2));
    }
    size_t ob = (((size_t)b * NDIM + h) * NT + t) * 32;
    #pragma unroll
    for (int j = 0; j < 8; ++j) {
        ushort4 hv = { hb[j*4], hb[j*4+1], hb[j*4+2], hb[j*4+3] };
        ushort4 lv = { lb[j*4], lb[j*4+1], lb[j*4+2], lb[j*4+3] };
        *(ushort4*)(oh + ob + j * 4) = hv;
        *(ushort4*)(ol + ob + j * 4) = lv;
    }
}

// ---------------- MFMA implicit-GEMM conv 32->32 3x3 (NHWC bf16 hi/lo) ----------------
// VAR 0: conv1b (H=192, 1x1-skip from hcat, pool, out NHWC 96 rows)
// VAR 1: conv2a (H=96, no skip, no pool, out NHWC 96 rows)
// VAR 2: conv2b (H=96, identity skip from S planes, pool, out RES f32 (B,T,1536))
template<int VAR>
__global__ __launch_bounds__(256) void k_convmfma(
    const u16* __restrict__ Xh, const u16* __restrict__ Xl,
    const u16* __restrict__ CWh, const u16* __restrict__ CWl,
    const float* __restrict__ hcat, const float* __restrict__ sw, const float* __restrict__ sb,
    const u16* __restrict__ Sh, const u16* __restrict__ Sl,
    const float* __restrict__ bias,
    u16* __restrict__ Oh, u16* __restrict__ Ol,
    float* __restrict__ RES,
    const u16* __restrict__ zeropad)
{
    constexpr int HIN = (VAR == 0) ? 192 : 96;
    __shared__ __align__(16) u16 lds[2][8448];   // [plane][4 rows][66 pos][32 ci], 33792 B
    const int t0 = blockIdx.x * 64;
    const int ho = blockIdx.y;
    const int b  = blockIdx.z;
    const int tid = threadIdx.x;
    const int wid = tid >> 6, lane = tid & 63;
    const int r0 = 2 * ho - 1;

    // ---- stage 2112 16B-chunks (2 planes x 1056), linear LDS dest, swizzled source ----
    for (int cb = wid * 64; cb < 2112; cb += 256) {
        int c = cb + lane;
        int plane = (c >= 1056) ? 1 : 0;
        int cc = c - plane * 1056;
        int row = cc / 264;
        int rc  = cc - row * 264;
        int pos = rc >> 2;
        int slot = rc & 3;
        int cib = slot ^ ((pos >> 1) & 3);
        int h = r0 + row;
        int t = t0 - 1 + pos;
        const u16* bp = plane ? Xl : Xh;
        const u16* src = (h >= 0 && h < HIN && t >= 0 && t < NT)
            ? bp + (((size_t)(b * HIN + h)) * NT + t) * 32 + cib * 8
            : zeropad;
        u16* ldst = &lds[0][0] + (size_t)cb * 8;   // uniform base; HW adds lane*16B
        GLD(src, ldst);
    }
    __syncthreads();

    // ---- compute: wave = t-tile (16 positions), 2 rows x 32 cout ----
    const int fr = lane & 15, fq = lane >> 4;
    f32x4 acc[2][2];
    #pragma unroll
    for (int pr = 0; pr < 2; ++pr)
        #pragma unroll
        for (int mt = 0; mt < 2; ++mt) acc[pr][mt] = (f32x4){0.f, 0.f, 0.f, 0.f};

    #pragma unroll
    for (int dh = 0; dh < 3; ++dh) {
        #pragma unroll
        for (int dt = 0; dt < 3; ++dt) {
            int tap = dh * 3 + dt;
            bf16x8 wh[2], wl[2];
            #pragma unroll
            for (int mt = 0; mt < 2; ++mt) {
                size_t wo = ((size_t)tap * 32 + mt * 16 + fr) * 32 + fq * 8;
                wh[mt] = *(const bf16x8*)(CWh + wo);
                wl[mt] = *(const bf16x8*)(CWl + wo);
            }
            int p = (wid << 4) + fr + dt;
            int sl = fq ^ ((p >> 1) & 3);
            #pragma unroll
            for (int pr = 0; pr < 2; ++pr) {
                int rr = pr + dh;
                const u16* lp = &lds[0][0] + ((rr * 66 + p) * 4 + sl) * 8;
                bf16x8 xh = *(const bf16x8*)lp;
                bf16x8 xl = *(const bf16x8*)(lp + 8448);
                #pragma unroll
                for (int mt = 0; mt < 2; ++mt) {
                    acc[pr][mt] = __builtin_amdgcn_mfma_f32_16x16x32_bf16(wh[mt], xh, acc[pr][mt], 0, 0, 0);
                    acc[pr][mt] = __builtin_amdgcn_mfma_f32_16x16x32_bf16(wh[mt], xl, acc[pr][mt], 0, 0, 0);
                    acc[pr][mt] = __builtin_amdgcn_mfma_f32_16x16x32_bf16(wl[mt], xh, acc[pr][mt], 0, 0, 0);
                }
            }
        }
    }

    // ---- epilogue ----
    const int t = t0 + (wid << 4) + fr;
    float hc0 = 0.f, hc1 = 0.f;
    if (VAR == 0) {
        hc0 = hcat[((size_t)(b * NDIM + 2 * ho    )) * NT + t];
        hc1 = hcat[((size_t)(b * NDIM + 2 * ho + 1)) * NT + t];
    }
    #pragma unroll
    for (int mt = 0; mt < 2; ++mt) {
        float v0[4], v1[4];
        if (VAR == 2) {
            ushort4 s0h = *(const ushort4*)(Sh + (((size_t)(b * 96 + 2 * ho    )) * NT + t) * 32 + mt * 16 + fq * 4);
            ushort4 s0l = *(const ushort4*)(Sl + (((size_t)(b * 96 + 2 * ho    )) * NT + t) * 32 + mt * 16 + fq * 4);
            ushort4 s1h = *(const ushort4*)(Sh + (((size_t)(b * 96 + 2 * ho + 1)) * NT + t) * 32 + mt * 16 + fq * 4);
            ushort4 s1l = *(const ushort4*)(Sl + (((size_t)(b * 96 + 2 * ho + 1)) * NT + t) * 32 + mt * 16 + fq * 4);
            v0[0] = bf2f(s0h.x) + bf2f(s0l.x); v0[1] = bf2f(s0h.y) + bf2f(s0l.y);
            v0[2] = bf2f(s0h.z) + bf2f(s0l.z); v0[3] = bf2f(s0h.w) + bf2f(s0l.w);
            v1[0] = bf2f(s1h.x) + bf2f(s1l.x); v1[1] = bf2f(s1h.y) + bf2f(s1l.y);
            v1[2] = bf2f(s1h.z) + bf2f(s1l.z); v1[3] = bf2f(s1h.w) + bf2f(s1l.w);
        }
        u16 hs[4], ls[4];
        float r0v[4], r1v[4];
        #pragma unroll
        for (int r = 0; r < 4; ++r) {
            int c = mt * 16 + fq * 4 + r;
            float a0 = acc[0][mt][r] + bias[c];
            float a1 = acc[1][mt][r] + bias[c];
            if (VAR == 0) {
                a0 += fmaf(hc0, sw[c], sb[c]);
                a1 += fmaf(hc1, sw[c], sb[c]);
            }
            if (VAR == 2) { a0 += v0[r]; a1 += v1[r]; }
            a0 = siluf(a0); a1 = siluf(a1);
            if (VAR == 1) { r0v[r] = a0; r1v[r] = a1; }
            else {
                float m = fmaxf(a0, a1);
                if (VAR == 2) r0v[r] = m;
                else { u16 hh = f2bf(m); hs[r] = hh; ls[r] = f2bf(m - bf2f(hh)); }
            }
        }
        if (VAR == 0) {
            size_t ob = (((size_t)(b * 96 + ho)) * NT + t) * 32 + mt * 16 + fq * 4;
            ushort4 hv = { hs[0], hs[1], hs[2], hs[3] };
            ushort4 lv = { ls[0], ls[1], ls[2], ls[3] };
            *(ushort4*)(Oh + ob) = hv;
            *(ushort4*)(Ol + ob) = lv;
        } else if (VAR == 1) {
            #pragma unroll
            for (int pr = 0; pr < 2; ++pr) {
                size_t ob = (((size_t)(b * 96 + 2 * ho + pr)) * NT + t) * 32 + mt * 16 + fq * 4;
                u16 hh[4], ll[4];
                #pragma unroll
                for (int r = 0; r < 4; ++r) {
                    float m = pr ? r1v[r] : r0v[r];
                    hh[r] = f2bf(m); ll[r] = f2bf(m - bf2f(hh[r]));
                }
                ushort4 hv = { hh[0], hh[1], hh[2], hh[3] };
                ushort4 lv = { ll[0], ll[1], ll[2], ll[3] };
                *(ushort4*)(Oh + ob) = hv;
                *(ushort4*)(Ol + ob) = lv;
            }
        } else {
            #pragma unroll
            for (int r = 0; r < 4; ++r) {
                int c = mt * 16 + fq * 4 + r;
                RES[((size_t)b * NT + t) * DMODEL + c * 48 + ho] = r0v[r];
            }
        }
    }
}

// ---------------- rmsnorm over D_MODEL -> bf16 hi/lo planes ----------------
__global__ __launch_bounds__(256) void k_rmsnorm(const float* __restrict__ in,
    const float* __restrict__ w, u16* __restrict__ oh, u16* __restrict__ ol)
{
    int row = blockIdx.x;
    int tid = threadIdx.x;
    const float* p = in + (size_t)row * DMODEL;
    float v[6]; float ss = 0.f;
    #pragma unroll
    for (int j = 0; j < 6; ++j) { v[j] = p[tid + j * 256]; ss = fmaf(v[j], v[j], ss); }
    #pragma unroll
    for (int off = 1; off < 64; off <<= 1) ss += __shfl_xor(ss, off);
    __shared__ float red[4];
    int lane = tid & 63, wv = tid >> 6;
    if (lane == 0) red[wv] = ss;
    __syncthreads();
    float tot = red[0] + red[1] + red[2] + red[3];
    float sc = rsqrtf(tot * (1.0f / DMODEL) + 1e-5f);
    #pragma unroll
    for (int j = 0; j < 6; ++j) {
        int col = tid + j * 256;
        float xv = v[j] * sc * w[col];
        u16 h = f2bf(xv);
        oh[(size_t)row * DMODEL + col] = h;
        ol[(size_t)row * DMODEL + col] = f2bf(xv - bf2f(h));
    }
}

// ---------------- split fp32 -> bf16 hi/lo (n divisible by 4) ----------------
__global__ __launch_bounds__(256) void k_split(const float* __restrict__ src,
    u16* __restrict__ dh, u16* __restrict__ dl, int n4)
{
    int idx = blockIdx.x * 256 + threadIdx.x;
    if (idx >= n4) return;
    float4 v = ((const float4*)src)[idx];
    u16 h0 = f2bf(v.x), h1 = f2bf(v.y), h2 = f2bf(v.z), h3 = f2bf(v.w);
    u16 l0 = f2bf(v.x - bf2f(h0)), l1 = f2bf(v.y - bf2f(h1));
    u16 l2 = f2bf(v.z - bf2f(h2)), l3 = f2bf(v.w - bf2f(h3));
    uint2 hv = { (u32)h0 | ((u32)h1 << 16), (u32)h2 | ((u32)h3 << 16) };
    uint2 lv = { (u32)l0 | ((u32)l1 << 16), (u32)l2 | ((u32)l3 << 16) };
    ((uint2*)dh)[idx] = hv;
    ((uint2*)dl)[idx] = lv;
}

// ---------------- split dt_w [3072][96] -> padded [3072][128] hi/lo ----------------
__global__ __launch_bounds__(256) void k_wsplit_pad(const float* __restrict__ src,
    u16* __restrict__ dh, u16* __restrict__ dl)
{
    int idx = blockIdx.x * 256 + threadIdx.x;
    if (idx >= DINNER * 128) return;
    int col = idx & 127, row = idx >> 7;
    float v = (col < DTRANK) ? src[(size_t)row * DTRANK + col] : 0.f;
    u16 h = f2bf(v);
    dh[idx] = h;
    dl[idx] = f2bf(v - bf2f(h));
}

// ---------------- MFMA GEMM: C[M,N] = A[M,K] * B[N,K]^T, 3-product bf16 ----------------
template<int EPI>
__global__ __launch_bounds__(256) void k_gemm_mfma(
    const u16* __restrict__ Ahi, const u16* __restrict__ Alo, int lda,
    const u16* __restrict__ Bhi, const u16* __restrict__ Blo, int ldb,
    float* __restrict__ C, int ldc, int Ktot,
    const float* __restrict__ bias, size_t zStride)
{
    __shared__ __align__(16) u16 lds[4][8192];
    const int tid = threadIdx.x;
    const int m0 = blockIdx.y * 128, n0 = blockIdx.x * 128;
    const int kPer = Ktot / gridDim.z;
    const int kBase = blockIdx.z * kPer;
    const int wid = tid >> 6, lane = tid & 63;
    const int wr = wid >> 1, wc = wid & 1;
    const int fr = lane & 15, fq = lane >> 4;
    const int srow  = tid >> 3;
    const int sslot = (tid & 7) ^ ((tid >> 3) & 7);

    f32x4 acc[4][4];
    #pragma unroll
    for (int mi = 0; mi < 4; ++mi)
        #pragma unroll
        for (int ni = 0; ni < 4; ++ni) acc[mi][ni] = (f32x4){0.f, 0.f, 0.f, 0.f};

    for (int k0 = kBase; k0 < kBase + kPer; k0 += 64) {
        #pragma unroll
        for (int i = 0; i < 4; ++i) {
            int row = i * 32 + srow;
            size_t offA = (size_t)(m0 + row) * lda + k0 + sslot * 8;
            size_t offB = (size_t)(n0 + row) * ldb + k0 + sslot * 8;
            u16* lb = &lds[0][0] + i * 2048 + (wid << 9);
            GLD(Ahi + offA, lb);
            GLD(Alo + offA, lb + 8192);
            GLD(Bhi + offB, lb + 16384);
            GLD(Blo + offB, lb + 24576);
        }
        __syncthreads();
        #pragma unroll
        for (int h = 0; h < 2; ++h) {
            bf16x8 ah[4], al[4], bh[4], bl[4];
            #pragma unroll
            for (int mi = 0; mi < 4; ++mi) {
                int row = wr * 64 + mi * 16 + fr;
                int sl  = (h * 4 + fq) ^ (row & 7);
                const u16* p = &lds[0][row * 64 + sl * 8];
                ah[mi] = *(const bf16x8*)p;
                al[mi] = *(const bf16x8*)(p + 8192);
            }
            #pragma unroll
            for (int ni = 0; ni < 4; ++ni) {
                int row = wc * 64 + ni * 16 + fr;
                int sl  = (h * 4 + fq) ^ (row & 7);
                const u16* p = &lds[2][row * 64 + sl * 8];
                bh[ni] = *(const bf16x8*)p;
                bl[ni] = *(const bf16x8*)(p + 8192);
            }
            #pragma unroll
            for (int mi = 0; mi < 4; ++mi)
                #pragma unroll
                for (int ni = 0; ni < 4; ++ni) {
                    acc[mi][ni] = __builtin_amdgcn_mfma_f32_16x16x32_bf16(ah[mi], bh[ni], acc[mi][ni], 0, 0, 0);
                    acc[mi][ni] = __builtin_amdgcn_mfma_f32_16x16x32_bf16(ah[mi], bl[ni], acc[mi][ni], 0, 0, 0);
                    acc[mi][ni] = __builtin_amdgcn_mfma_f32_16x16x32_bf16(al[mi], bh[ni], acc[mi][ni], 0, 0, 0);
                }
        }
        __syncthreads();
    }

    float* Cz = C + (EPI == 0 ? (size_t)blockIdx.z * zStride : (size_t)0);
    #pragma unroll
    for (int mi = 0; mi < 4; ++mi)
        #pragma unroll
        for (int ni = 0; ni < 4; ++ni) {
            int gr = m0 + wr * 64 + mi * 16 + fq * 4;
            int gc = n0 + wc * 64 + ni * 16 + fr;
            float* cp = Cz + (size_t)gr * ldc + gc;
            #pragma unroll
            for (int r = 0; r < 4; ++r) {
                float v = acc[mi][ni][r];
                if (EPI == 1) v = softplusf(v + bias[gc]);
                if (EPI == 2) v += cp[(size_t)r * ldc];
                cp[(size_t)r * ldc] = v;
            }
        }
}

// ---------------- depthwise causal conv1d(k=4)+bias+silu -> u hi/lo ----------------
__global__ __launch_bounds__(256) void k_conv1d(
    const float* __restrict__ xz, const float* __restrict__ w,
    const float* __restrict__ bias, u16* __restrict__ uh, u16* __restrict__ ul)
{
    int idx = blockIdx.x * 256 + threadIdx.x;
    if (idx >= NB * NT * (DINNER / 4)) return;
    int dv = idx % (DINNER / 4);
    int t  = (idx / (DINNER / 4)) % NT;
    int b  = idx / ((DINNER / 4) * NT);
    int d  = dv * 4;
    const float* base = xz + ((size_t)b * NT + t) * (2 * DINNER) + d;
    float4 a[4];
    #pragma unroll
    for (int k = 0; k < 4; ++k) {
        int tm = t - 3 + k;
        if (tm >= 0) a[k] = *(const float4*)(base + (ptrdiff_t)(k - 3) * (2 * DINNER));
        else         a[k] = make_float4(0.f, 0.f, 0.f, 0.f);
    }
    float4 w0 = *(const float4*)(w + (size_t)(d + 0) * 4);
    float4 w1 = *(const float4*)(w + (size_t)(d + 1) * 4);
    float4 w2 = *(const float4*)(w + (size_t)(d + 2) * 4);
    float4 w3 = *(const float4*)(w + (size_t)(d + 3) * 4);
    float4 bb = *(const float4*)(bias + d);
    float o0 = siluf(bb.x + a[0].x * w0.x + a[1].x * w0.y + a[2].x * w0.z + a[3].x * w0.w);
    float o1 = siluf(bb.y + a[0].y * w1.x + a[1].y * w1.y + a[2].y * w1.z + a[3].y * w1.w);
    float o2 = siluf(bb.z + a[0].z * w2.x + a[1].z * w2.y + a[2].z * w2.z + a[3].z * w2.w);
    float o3 = siluf(bb.w + a[0].w * w3.x + a[1].w * w3.y + a[2].w * w3.z + a[3].w * w3.w);
    u16 h0 = f2bf(o0), h1 = f2bf(o1), h2 = f2bf(o2), h3 = f2bf(o3);
    u16 l0 = f2bf(o0 - bf2f(h0)), l1 = f2bf(o1 - bf2f(h1));
    u16 l2 = f2bf(o2 - bf2f(h2)), l3 = f2bf(o3 - bf2f(h3));
    size_t ob = ((size_t)b * NT + t) * DINNER + d;
    uint2 hv = { (u32)h0 | ((u32)h1 << 16), (u32)h2 | ((u32)h3 << 16) };
    uint2 lv = { (u32)l0 | ((u32)l1 << 16), (u32)l2 | ((u32)l3 << 16) };
    *(uint2*)(uh + ob) = hv;
    *(uint2*)(ul + ob) = lv;
}

// ---------------- reduce 4 split-K slabs of x_proj ----------------
__global__ __launch_bounds__(256) void k_reduce4(const float* __restrict__ part,
                                                 float* __restrict__ out)
{
    int idx = blockIdx.x * 256 + threadIdx.x;
    if (idx >= MROWS * 128) return;
    float s = part[idx] + part[(size_t)1 * MROWS * 128 + idx]
            + part[(size_t)2 * MROWS * 128 + idx] + part[(size_t)3 * MROWS * 128 + idx];
    out[idx] = s;
}

// ---------------- selective scan + gating -> y hi/lo (in place over u planes) ----------------
__global__ __launch_bounds__(256) void k_scan(
    const float* __restrict__ xz,
    u16* uh, u16* ul,
    const float* __restrict__ xdbl,
    const float* __restrict__ A_log, const float* __restrict__ Dp)
{
    const int tid = threadIdx.x;
    const int g = tid >> 3;
    const int i = tid & 7;
    const int d = blockIdx.x * 32 + g;
    const int b = blockIdx.y;
    const float L2E = 1.44269504088896340736f;
    float aa0 = -__expf(A_log[d * DSTATE + 2 * i    ]) * L2E;
    float aa1 = -__expf(A_log[d * DSTATE + 2 * i + 1]) * L2E;
    const float dp = Dp[d];
    const float* dP = xz + (size_t)b * NT * (2 * DINNER) + d;
    const float* zP = dP + DINNER;
    const u16* uhP = uh + (size_t)b * NT * DINNER + d;
    const u16* ulP = ul + (size_t)b * NT * DINNER + d;
    u16* yhP = (u16*)uhP;
    u16* ylP = (u16*)ulP;
    const float* bP = xdbl + (size_t)b * NT * 128 + DTRANK + 2 * i;
    const float* cP = bP + DSTATE;
    float h0 = 0.f, h1 = 0.f;
    float dlt = dP[0], zz = zP[0];
    float uu = bf2f(uhP[0]) + bf2f(ulP[0]);
    float2 Bf = *(const float2*)bP;
    float2 Cf = *(const float2*)cP;
    for (int t = 0; t < NT; ++t) {
        float dlt_n = 0.f, uu_n = 0.f, zz_n = 0.f;
        float2 Bn = {0.f, 0.f}, Cn = {0.f, 0.f};
        if (t + 1 < NT) {
            dlt_n = dP[2 * DINNER]; zz_n = zP[2 * DINNER];
            uu_n = bf2f(uhP[DINNER]) + bf2f(ulP[DINNER]);
            Bn = *(const float2*)(bP + 128); Cn = *(const float2*)(cP + 128);
        }
        float du = dlt * uu;
        h0 = fmaf(exp2f(dlt * aa0), h0, du * Bf.x);
        h1 = fmaf(exp2f(dlt * aa1), h1, du * Bf.y);
        float p = fmaf(h0, Cf.x, h1 * Cf.y);
        p += __shfl_xor(p, 1);
        p += __shfl_xor(p, 2);
        p += __shfl_xor(p, 4);
        if (i == 0) {
            float yv = (p + uu * dp) * siluf(zz);
            u16 hh = f2bf(yv);
            yhP[0] = hh;
            ylP[0] = f2bf(yv - bf2f(hh));
        }
        dP += 2 * DINNER; zP += 2 * DINNER;
        uhP += DINNER; ulP += DINNER; yhP += DINNER; ylP += DINNER;
        bP += 128; cP += 128;
        dlt = dlt_n; zz = zz_n; uu = uu_n; Bf = Bn; Cf = Cn;
    }
}

// ---------------- final fc + silu + transpose to (B,5,T) ----------------
__global__ __launch_bounds__(256) void k_fc(const float* __restrict__ hR,
    const float* __restrict__ w, const float* __restrict__ bias,
    float* __restrict__ out)
{
    int row = blockIdx.x;
    int tid = threadIdx.x;
    const float* p = hR + (size_t)row * DMODEL;
    float acc[NCLASS] = {0.f, 0.f, 0.f, 0.f, 0.f};
    #pragma unroll
    for (int j = 0; j < 6; ++j) {
        int col = tid + j * 256;
        float v = p[col];
        #pragma unroll
        for (int c = 0; c < NCLASS; ++c)
            acc[c] = fmaf(v, w[c * DMODEL + col], acc[c]);
    }
    #pragma unroll
    for (int c = 0; c < NCLASS; ++c)
        #pragma unroll
        for (int off = 1; off < 64; off <<= 1)
            acc[c] += __shfl_xor(acc[c], off);
    __shared__ float red[4][NCLASS];
    int lane = tid & 63, wv = tid >> 6;
    if (lane == 0)
        for (int c = 0; c < NCLASS; ++c) red[wv][c] = acc[c];
    __syncthreads();
    if (tid < NCLASS) {
        float s = red[0][tid] + red[1][tid] + red[2][tid] + red[3][tid] + bias[tid];
        int b = row >> 10, t = row & (NT - 1);
        out[((size_t)b * NCLASS + tid) * NT + t] = siluf(s);
    }
}

extern "C" void kernel_launch(void* const* d_in, const int* in_sizes, int n_in,
                              void* d_out, int out_size, void* d_ws, size_t ws_size,
                              hipStream_t stream)
{
    const float* x      = (const float*)d_in[0];
    const float* c1a_w  = (const float*)d_in[1];
    const float* c1a_b  = (const float*)d_in[2];
    const float* c1b_w  = (const float*)d_in[3];
    const float* c1b_b  = (const float*)d_in[4];
    const float* c1s_w  = (const float*)d_in[5];
    const float* c1s_b  = (const float*)d_in[6];
    const float* c2a_w  = (const float*)d_in[7];
    const float* c2a_b  = (const float*)d_in[8];
    const float* c2b_w  = (const float*)d_in[9];
    const float* c2b_b  = (const float*)d_in[10];
    const float* norm_w = (const float*)d_in[11];
    const float* in_w   = (const float*)d_in[12];
    const float* conv_w = (const float*)d_in[13];
    const float* conv_b = (const float*)d_in[14];
    const float* xproj_w= (const float*)d_in[15];
    const float* dt_w   = (const float*)d_in[16];
    const float* dt_b   = (const float*)d_in[17];
    const float* A_log  = (const float*)d_in[18];
    const float* Dp     = (const float*)d_in[19];
    const float* out_w  = (const float*)d_in[20];
    const float* fc_w   = (const float*)d_in[21];
    const float* fc_b   = (const float*)d_in[22];
    float* outp = (float*)d_out;
    (void)in_sizes; (void)n_in; (void)out_size; (void)ws_size;

    char* base = (char*)d_ws;
    size_t off = 0;
    auto takeB = [&](size_t bytes) { void* p = base + off; off = (off + bytes + 255) & ~(size_t)255; return p; };
    float* HCAT = (float*)takeB((size_t)NB * NDIM * NT * 4);          // 6.3 MB
    float* XZ   = (float*)takeB((size_t)MROWS * 2 * DINNER * 4);      // 201 MB (T1/T3 NHWC planes; xz)
    float* RES  = (float*)takeB((size_t)MROWS * DMODEL * 4);          // 50 MB
    u16*   XNh  = (u16*)takeB((size_t)MROWS * DMODEL * 2);            // 25 MB
    u16*   XNl  = (u16*)takeB((size_t)MROWS * DMODEL * 2);            // 25 MB
    u16*   Uh   = (u16*)takeB((size_t)MROWS * DINNER * 2);            // 50 MB (P1h / u / y)
    u16*   Ul   = (u16*)takeB((size_t)MROWS * DINNER * 2);            // 50 MB (P1l)
    float* XDBL = (float*)takeB((size_t)MROWS * 128 * 4);             // 4.2 MB
    float* XPART= (float*)takeB((size_t)4 * MROWS * 128 * 4);         // 16.8 MB
    u16*   XDh  = (u16*)takeB((size_t)MROWS * 128 * 2);               // 2.1 MB
    u16*   XDl  = (u16*)takeB((size_t)MROWS * 128 * 2);               // 2.1 MB
    u16*   Wh   = (u16*)takeB((size_t)9437184 * 2);                   // 18.9 MB
    u16*   Wl   = (u16*)takeB((size_t)9437184 * 2);                   // 18.9 MB
    u16*   CW1h = (u16*)takeB(18432);
    u16*   CW1l = (u16*)takeB(18432);
    u16*   CW2h = (u16*)takeB(18432);
    u16*   CW2l = (u16*)takeB(18432);
    u16*   CW3h = (u16*)takeB(18432);
    u16*   CW3l = (u16*)takeB(18432);
    u16*   ZPAD = (u16*)takeB(256);

    // CNN activation aliases
    u16* T1h = (u16*)XZ;                       // (8,192,1024,32)
    u16* T1l = T1h + (size_t)NB * NDIM * NT * 32;
    u16* T3h = (u16*)XZ;                       // (8,96,1024,32) — T1 dead by then
    u16* T3l = T3h + (size_t)NB * NDIM * NT * 32;
    u16* P1h = Uh;                             // (8,96,1024,32)
    u16* P1l = Ul;

    const int n1 = NB * NDIM * NT;
    k_zero<<<1, 128, 0, stream>>>(ZPAD);
    k_prep  <<<(n1 + 255) / 256, 256, 0, stream>>>(x, HCAT);
    k_wconv<<<36, 256, 0, stream>>>(c1b_w, CW1h, CW1l);
    k_wconv<<<36, 256, 0, stream>>>(c2a_w, CW2h, CW2l);
    k_wconv<<<36, 256, 0, stream>>>(c2b_w, CW3h, CW3l);
    k_conv1a<<<(n1 + 255) / 256, 256, 0, stream>>>(HCAT, c1a_w, c1a_b, T1h, T1l);
    k_convmfma<0><<<dim3(16, 96, NB), 256, 0, stream>>>(
        T1h, T1l, CW1h, CW1l, HCAT, c1s_w, c1s_b, nullptr, nullptr,
        c1b_b, P1h, P1l, nullptr, ZPAD);
    k_convmfma<1><<<dim3(16, 48, NB), 256, 0, stream>>>(
        P1h, P1l, CW2h, CW2l, nullptr, nullptr, nullptr, nullptr, nullptr,
        c2a_b, T3h, T3l, nullptr, ZPAD);
    k_convmfma<2><<<dim3(16, 48, NB), 256, 0, stream>>>(
        T3h, T3l, CW3h, CW3l, nullptr, nullptr, nullptr, P1h, P1l,
        c2b_b, nullptr, nullptr, RES, ZPAD);

    for (int l = 0; l < NLAYER; ++l) {
        k_rmsnorm<<<MROWS, 256, 0, stream>>>(RES, norm_w + (size_t)l * DMODEL, XNh, XNl);
        k_split<<<(9437184 / 4 + 255) / 256, 256, 0, stream>>>(
            in_w + (size_t)l * 2 * DINNER * DMODEL, Wh, Wl, 9437184 / 4);
        k_gemm_mfma<0><<<dim3(2 * DINNER / 128, MROWS / 128, 1), 256, 0, stream>>>(
            XNh, XNl, DMODEL, Wh, Wl, DMODEL, XZ, 2 * DINNER, DMODEL, nullptr, 0);
        k_conv1d<<<(NB * NT * (DINNER / 4) + 255) / 256, 256, 0, stream>>>(
            XZ, conv_w + (size_t)l * DINNER * 4, conv_b + (size_t)l * DINNER, Uh, Ul);
        k_split<<<(393216 / 4 + 255) / 256, 256, 0, stream>>>(
            xproj_w + (size_t)l * 128 * DINNER, Wh, Wl, 393216 / 4);
        k_gemm_mfma<0><<<dim3(1, MROWS / 128, 4), 256, 0, stream>>>(
            Uh, Ul, DINNER, Wh, Wl, DINNER, XPART, 128, DINNER, nullptr, (size_t)MROWS * 128);
        k_reduce4<<<(MROWS * 128 + 255) / 256, 256, 0, stream>>>(XPART, XDBL);
        k_split<<<(MROWS * 128 / 4 + 255) / 256, 256, 0, stream>>>(XDBL, XDh, XDl, MROWS * 128 / 4);
        k_wsplit_pad<<<(DINNER * 128 + 255) / 256, 256, 0, stream>>>(
            dt_w + (size_t)l * DINNER * DTRANK, Wh, Wl);
        k_gemm_mfma<1><<<dim3(DINNER / 128, MROWS / 128, 1), 256, 0, stream>>>(
            XDh, XDl, 128, Wh, Wl, 128, XZ, 2 * DINNER, 128,
            dt_b + (size_t)l * DINNER, 0);
        k_scan<<<dim3(DINNER / 32, NB), 256, 0, stream>>>(
            XZ, Uh, Ul, XDBL, A_log + (size_t)l * DINNER * DSTATE, Dp + (size_t)l * DINNER);
        k_split<<<(4718592 / 4 + 255) / 256, 256, 0, stream>>>(
            out_w + (size_t)l * DMODEL * DINNER, Wh, Wl, 4718592 / 4);
        k_gemm_mfma<2><<<dim3(DMODEL / 128, MROWS / 128, 1), 256, 0, stream>>>(
            Uh, Ul, DINNER, Wh, Wl, DINNER, RES, DMODEL, DINNER, nullptr, 0);
    }
    k_fc<<<MROWS, 256, 0, stream>>>(RES, fc_w, fc_b, outp);
}

// Round 4
// 6519.099 us; speedup vs baseline: 2.8525x; 1.0874x over previous
//
#include <hip/hip_runtime.h>
#include <cstdint>
#include <cstddef>

#define DEV static __device__ __forceinline__

typedef unsigned short u16;
typedef unsigned int   u32;
typedef __bf16 bf16x8 __attribute__((ext_vector_type(8)));
typedef float  f32x4  __attribute__((ext_vector_type(4)));

namespace {
constexpr int NB     = 8;
constexpr int NT     = 1024;
constexpr int NMEL   = 96;
constexpr int NDIM   = 192;
constexpr int NCH    = 32;
constexpr int DMODEL = 1536;
constexpr int DINNER = 3072;
constexpr int DSTATE = 16;
constexpr int DTRANK = 96;
constexpr int NLAYER = 4;
constexpr int NCLASS = 5;
constexpr int MROWS  = NB * NT;   // 8192
constexpr int NCHK   = 8;
constexpr int CHKT   = NT / NCHK; // 128
}

DEV float siluf(float x)    { return x / (1.0f + __expf(-x)); }
DEV float softplusf(float x){ return fmaxf(x, 0.0f) + log1pf(__expf(-fabsf(x))); }

DEV u16 f2bf(float f) {
    u32 u = __float_as_uint(f);
    u32 r = u + 0x7FFFu + ((u >> 16) & 1u);
    return (u16)(r >> 16);
}
DEV float bf2f(u16 h) { return __uint_as_float(((u32)h) << 16); }

#define GLD(gp, lp) __builtin_amdgcn_global_load_lds( \
    (const __attribute__((address_space(1))) u32*)(const void*)(gp), \
    (__attribute__((address_space(3))) u32*)(void*)(lp), 16, 0, 0)

// ---------------- zero pad buffer ----------------
__global__ void k_zero(u16* p) { p[threadIdx.x] = 0; }

// ---------------- prep: x -> hcat (B,192,T): [x ; relu(diff)] ----------------
__global__ __launch_bounds__(256) void k_prep(const float* __restrict__ x,
                                              float* __restrict__ hcat)
{
    int idx = blockIdx.x * 256 + threadIdx.x;
    if (idx >= NB * NDIM * NT) return;
    int t = idx & (NT - 1);
    int m = (idx >> 10) % NDIM;
    int b = idx / (NDIM * NT);
    float v;
    if (m < NMEL) {
        v = x[((size_t)b * NMEL + m) * NT + t];
    } else {
        int mm = m - NMEL;
        v = 0.f;
        if (t > 0) {
            const float* p = x + ((size_t)b * NMEL + mm) * NT + t;
            v = fmaxf(p[0] - p[-1], 0.f);
        }
    }
    hcat[idx] = v;
}

// ---------------- conv weight prep: (32,32,3,3) -> [tap][cout][ci] hi/lo ----------------
__global__ __launch_bounds__(256) void k_wconv(const float* __restrict__ w,
    u16* __restrict__ dh, u16* __restrict__ dl)
{
    int idx = blockIdx.x * 256 + threadIdx.x;
    if (idx >= 9216) return;
    int ci = idx & 31, cout = (idx >> 5) & 31, tap = idx >> 10;
    float v = w[((size_t)cout * 32 + ci) * 9 + tap];
    u16 h = f2bf(v);
    dh[idx] = h;
    dl[idx] = f2bf(v - bf2f(h));
}

// ---------------- conv1a (1->32, 3x3) + silu -> NHWC bf16 hi/lo ----------------
__global__ __launch_bounds__(256) void k_conv1a(const float* __restrict__ hcat,
    const float* __restrict__ w, const float* __restrict__ bias,
    u16* __restrict__ oh, u16* __restrict__ ol)   // (B,192,T,32)
{
    int idx = blockIdx.x * 256 + threadIdx.x;
    if (idx >= NB * NDIM * NT) return;
    int t = idx & (NT - 1);
    int h = (idx >> 10) % NDIM;
    int b = idx / (NDIM * NT);
    float in[3][3];
    #pragma unroll
    for (int dh = 0; dh < 3; ++dh)
        #pragma unroll
        for (int dw = 0; dw < 3; ++dw) {
            int hh = h + dh - 1, tt = t + dw - 1;
            in[dh][dw] = (hh >= 0 && hh < NDIM && tt >= 0 && tt < NT)
                       ? hcat[((size_t)b * NDIM + hh) * NT + tt] : 0.f;
        }
    u16 hb[32], lb[32];
    #pragma unroll
    for (int c = 0; c < NCH; ++c) {
        float acc = bias[c];
        #pragma unroll
        for (int dh = 0; dh < 3; ++dh)
            #pragma unroll
            for (int dw = 0; dw < 3; ++dw)
                acc = fmaf(in[dh][dw], w[c * 9 + dh * 3 + dw], acc);
        float o = siluf(acc);
        u16 hh2 = f2bf(o);
        hb[c] = hh2;
        lb[c] = f2bf(o - bf2f(hh2));
    }
    size_t ob = (((size_t)b * NDIM + h) * NT + t) * 32;
    #pragma unroll
    for (int j = 0; j < 8; ++j) {
        ushort4 hv = { hb[j*4], hb[j*4+1], hb[j*4+2], hb[j*4+3] };
        ushort4 lv = { lb[j*4], lb[j*4+1], lb[j*4+2], lb[j*4+3] };
        *(ushort4*)(oh + ob + j * 4) = hv;
        *(ushort4*)(ol + ob + j * 4) = lv;
    }
}

// ---------------- MFMA implicit-GEMM conv 32->32 3x3 (NHWC bf16 hi/lo) ----------------
template<int VAR>
__global__ __launch_bounds__(256) void k_convmfma(
    const u16* __restrict__ Xh, const u16* __restrict__ Xl,
    const u16* __restrict__ CWh, const u16* __restrict__ CWl,
    const float* __restrict__ hcat, const float* __restrict__ sw, const float* __restrict__ sb,
    const u16* __restrict__ Sh, const u16* __restrict__ Sl,
    const float* __restrict__ bias,
    u16* __restrict__ Oh, u16* __restrict__ Ol,
    float* __restrict__ RES,
    const u16* __restrict__ zeropad)
{
    constexpr int HIN = (VAR == 0) ? 192 : 96;
    __shared__ __align__(16) u16 lds[2][8448];
    const int t0 = blockIdx.x * 64;
    const int ho = blockIdx.y;
    const int b  = blockIdx.z;
    const int tid = threadIdx.x;
    const int wid = tid >> 6, lane = tid & 63;
    const int r0 = 2 * ho - 1;

    for (int cb = wid * 64; cb < 2112; cb += 256) {
        int c = cb + lane;
        int plane = (c >= 1056) ? 1 : 0;
        int cc = c - plane * 1056;
        int row = cc / 264;
        int rc  = cc - row * 264;
        int pos = rc >> 2;
        int slot = rc & 3;
        int cib = slot ^ ((pos >> 1) & 3);
        int h = r0 + row;
        int t = t0 - 1 + pos;
        const u16* bp = plane ? Xl : Xh;
        const u16* src = (h >= 0 && h < HIN && t >= 0 && t < NT)
            ? bp + (((size_t)(b * HIN + h)) * NT + t) * 32 + cib * 8
            : zeropad;
        u16* ldst = &lds[0][0] + (size_t)cb * 8;
        GLD(src, ldst);
    }
    __syncthreads();

    const int fr = lane & 15, fq = lane >> 4;
    f32x4 acc[2][2];
    #pragma unroll
    for (int pr = 0; pr < 2; ++pr)
        #pragma unroll
        for (int mt = 0; mt < 2; ++mt) acc[pr][mt] = (f32x4){0.f, 0.f, 0.f, 0.f};

    #pragma unroll
    for (int dh = 0; dh < 3; ++dh) {
        #pragma unroll
        for (int dt = 0; dt < 3; ++dt) {
            int tap = dh * 3 + dt;
            bf16x8 wh[2], wl[2];
            #pragma unroll
            for (int mt = 0; mt < 2; ++mt) {
                size_t wo = ((size_t)tap * 32 + mt * 16 + fr) * 32 + fq * 8;
                wh[mt] = *(const bf16x8*)(CWh + wo);
                wl[mt] = *(const bf16x8*)(CWl + wo);
            }
            int p = (wid << 4) + fr + dt;
            int sl = fq ^ ((p >> 1) & 3);
            #pragma unroll
            for (int pr = 0; pr < 2; ++pr) {
                int rr = pr + dh;
                const u16* lp = &lds[0][0] + ((rr * 66 + p) * 4 + sl) * 8;
                bf16x8 xh = *(const bf16x8*)lp;
                bf16x8 xl = *(const bf16x8*)(lp + 8448);
                #pragma unroll
                for (int mt = 0; mt < 2; ++mt) {
                    acc[pr][mt] = __builtin_amdgcn_mfma_f32_16x16x32_bf16(wh[mt], xh, acc[pr][mt], 0, 0, 0);
                    acc[pr][mt] = __builtin_amdgcn_mfma_f32_16x16x32_bf16(wh[mt], xl, acc[pr][mt], 0, 0, 0);
                    acc[pr][mt] = __builtin_amdgcn_mfma_f32_16x16x32_bf16(wl[mt], xh, acc[pr][mt], 0, 0, 0);
                }
            }
        }
    }

    const int t = t0 + (wid << 4) + fr;
    float hc0 = 0.f, hc1 = 0.f;
    if (VAR == 0) {
        hc0 = hcat[((size_t)(b * NDIM + 2 * ho    )) * NT + t];
        hc1 = hcat[((size_t)(b * NDIM + 2 * ho + 1)) * NT + t];
    }
    #pragma unroll
    for (int mt = 0; mt < 2; ++mt) {
        float v0[4], v1[4];
        if (VAR == 2) {
            ushort4 s0h = *(const ushort4*)(Sh + (((size_t)(b * 96 + 2 * ho    )) * NT + t) * 32 + mt * 16 + fq * 4);
            ushort4 s0l = *(const ushort4*)(Sl + (((size_t)(b * 96 + 2 * ho    )) * NT + t) * 32 + mt * 16 + fq * 4);
            ushort4 s1h = *(const ushort4*)(Sh + (((size_t)(b * 96 + 2 * ho + 1)) * NT + t) * 32 + mt * 16 + fq * 4);
            ushort4 s1l = *(const ushort4*)(Sl + (((size_t)(b * 96 + 2 * ho + 1)) * NT + t) * 32 + mt * 16 + fq * 4);
            v0[0] = bf2f(s0h.x) + bf2f(s0l.x); v0[1] = bf2f(s0h.y) + bf2f(s0l.y);
            v0[2] = bf2f(s0h.z) + bf2f(s0l.z); v0[3] = bf2f(s0h.w) + bf2f(s0l.w);
            v1[0] = bf2f(s1h.x) + bf2f(s1l.x); v1[1] = bf2f(s1h.y) + bf2f(s1l.y);
            v1[2] = bf2f(s1h.z) + bf2f(s1l.z); v1[3] = bf2f(s1h.w) + bf2f(s1l.w);
        }
        u16 hs[4], ls[4];
        float r0v[4], r1v[4];
        #pragma unroll
        for (int r = 0; r < 4; ++r) {
            int c = mt * 16 + fq * 4 + r;
            float a0 = acc[0][mt][r] + bias[c];
            float a1 = acc[1][mt][r] + bias[c];
            if (VAR == 0) {
                a0 += fmaf(hc0, sw[c], sb[c]);
                a1 += fmaf(hc1, sw[c], sb[c]);
            }
            if (VAR == 2) { a0 += v0[r]; a1 += v1[r]; }
            a0 = siluf(a0); a1 = siluf(a1);
            if (VAR == 1) { r0v[r] = a0; r1v[r] = a1; }
            else {
                float m = fmaxf(a0, a1);
                if (VAR == 2) r0v[r] = m;
                else { u16 hh = f2bf(m); hs[r] = hh; ls[r] = f2bf(m - bf2f(hh)); }
            }
        }
        if (VAR == 0) {
            size_t ob = (((size_t)(b * 96 + ho)) * NT + t) * 32 + mt * 16 + fq * 4;
            ushort4 hv = { hs[0], hs[1], hs[2], hs[3] };
            ushort4 lv = { ls[0], ls[1], ls[2], ls[3] };
            *(ushort4*)(Oh + ob) = hv;
            *(ushort4*)(Ol + ob) = lv;
        } else if (VAR == 1) {
            #pragma unroll
            for (int pr = 0; pr < 2; ++pr) {
                size_t ob = (((size_t)(b * 96 + 2 * ho + pr)) * NT + t) * 32 + mt * 16 + fq * 4;
                u16 hh[4], ll[4];
                #pragma unroll
                for (int r = 0; r < 4; ++r) {
                    float m = pr ? r1v[r] : r0v[r];
                    hh[r] = f2bf(m); ll[r] = f2bf(m - bf2f(hh[r]));
                }
                ushort4 hv = { hh[0], hh[1], hh[2], hh[3] };
                ushort4 lv = { ll[0], ll[1], ll[2], ll[3] };
                *(ushort4*)(Oh + ob) = hv;
                *(ushort4*)(Ol + ob) = lv;
            }
        } else {
            #pragma unroll
            for (int r = 0; r < 4; ++r) {
                int c = mt * 16 + fq * 4 + r;
                RES[((size_t)b * NT + t) * DMODEL + c * 48 + ho] = r0v[r];
            }
        }
    }
}

// ---------------- rmsnorm over D_MODEL -> bf16 hi/lo planes ----------------
__global__ __launch_bounds__(256) void k_rmsnorm(const float* __restrict__ in,
    const float* __restrict__ w, u16* __restrict__ oh, u16* __restrict__ ol)
{
    int row = blockIdx.x;
    int tid = threadIdx.x;
    const float* p = in + (size_t)row * DMODEL;
    float v[6]; float ss = 0.f;
    #pragma unroll
    for (int j = 0; j < 6; ++j) { v[j] = p[tid + j * 256]; ss = fmaf(v[j], v[j], ss); }
    #pragma unroll
    for (int off = 1; off < 64; off <<= 1) ss += __shfl_xor(ss, off);
    __shared__ float red[4];
    int lane = tid & 63, wv = tid >> 6;
    if (lane == 0) red[wv] = ss;
    __syncthreads();
    float tot = red[0] + red[1] + red[2] + red[3];
    float sc = rsqrtf(tot * (1.0f / DMODEL) + 1e-5f);
    #pragma unroll
    for (int j = 0; j < 6; ++j) {
        int col = tid + j * 256;
        float xv = v[j] * sc * w[col];
        u16 h = f2bf(xv);
        oh[(size_t)row * DMODEL + col] = h;
        ol[(size_t)row * DMODEL + col] = f2bf(xv - bf2f(h));
    }
}

// ---------------- split fp32 -> bf16 hi/lo (n divisible by 4) ----------------
__global__ __launch_bounds__(256) void k_split(const float* __restrict__ src,
    u16* __restrict__ dh, u16* __restrict__ dl, int n4)
{
    int idx = blockIdx.x * 256 + threadIdx.x;
    if (idx >= n4) return;
    float4 v = ((const float4*)src)[idx];
    u16 h0 = f2bf(v.x), h1 = f2bf(v.y), h2 = f2bf(v.z), h3 = f2bf(v.w);
    u16 l0 = f2bf(v.x - bf2f(h0)), l1 = f2bf(v.y - bf2f(h1));
    u16 l2 = f2bf(v.z - bf2f(h2)), l3 = f2bf(v.w - bf2f(h3));
    uint2 hv = { (u32)h0 | ((u32)h1 << 16), (u32)h2 | ((u32)h3 << 16) };
    uint2 lv = { (u32)l0 | ((u32)l1 << 16), (u32)l2 | ((u32)l3 << 16) };
    ((uint2*)dh)[idx] = hv;
    ((uint2*)dl)[idx] = lv;
}

// ---------------- split dt_w [3072][96] -> padded [3072][128] hi/lo ----------------
__global__ __launch_bounds__(256) void k_wsplit_pad(const float* __restrict__ src,
    u16* __restrict__ dh, u16* __restrict__ dl)
{
    int idx = blockIdx.x * 256 + threadIdx.x;
    if (idx >= DINNER * 128) return;
    int col = idx & 127, row = idx >> 7;
    float v = (col < DTRANK) ? src[(size_t)row * DTRANK + col] : 0.f;
    u16 h = f2bf(v);
    dh[idx] = h;
    dl[idx] = f2bf(v - bf2f(h));
}

// ---------------- MFMA GEMM: C[M,N] = A[M,K] * B[N,K]^T, 3-product bf16 ----------------
template<int EPI>
__global__ __launch_bounds__(256) void k_gemm_mfma(
    const u16* __restrict__ Ahi, const u16* __restrict__ Alo, int lda,
    const u16* __restrict__ Bhi, const u16* __restrict__ Blo, int ldb,
    float* __restrict__ C, int ldc, int Ktot,
    const float* __restrict__ bias, size_t zStride)
{
    __shared__ __align__(16) u16 lds[4][8192];
    const int tid = threadIdx.x;
    const int m0 = blockIdx.y * 128, n0 = blockIdx.x * 128;
    const int kPer = Ktot / gridDim.z;
    const int kBase = blockIdx.z * kPer;
    const int wid = tid >> 6, lane = tid & 63;
    const int wr = wid >> 1, wc = wid & 1;
    const int fr = lane & 15, fq = lane >> 4;
    const int srow  = tid >> 3;
    const int sslot = (tid & 7) ^ ((tid >> 3) & 7);

    f32x4 acc[4][4];
    #pragma unroll
    for (int mi = 0; mi < 4; ++mi)
        #pragma unroll
        for (int ni = 0; ni < 4; ++ni) acc[mi][ni] = (f32x4){0.f, 0.f, 0.f, 0.f};

    for (int k0 = kBase; k0 < kBase + kPer; k0 += 64) {
        #pragma unroll
        for (int i = 0; i < 4; ++i) {
            int row = i * 32 + srow;
            size_t offA = (size_t)(m0 + row) * lda + k0 + sslot * 8;
            size_t offB = (size_t)(n0 + row) * ldb + k0 + sslot * 8;
            u16* lb = &lds[0][0] + i * 2048 + (wid << 9);
            GLD(Ahi + offA, lb);
            GLD(Alo + offA, lb + 8192);
            GLD(Bhi + offB, lb + 16384);
            GLD(Blo + offB, lb + 24576);
        }
        __syncthreads();
        #pragma unroll
        for (int h = 0; h < 2; ++h) {
            bf16x8 ah[4], al[4], bh[4], bl[4];
            #pragma unroll
            for (int mi = 0; mi < 4; ++mi) {
                int row = wr * 64 + mi * 16 + fr;
                int sl  = (h * 4 + fq) ^ (row & 7);
                const u16* p = &lds[0][row * 64 + sl * 8];
                ah[mi] = *(const bf16x8*)p;
                al[mi] = *(const bf16x8*)(p + 8192);
            }
            #pragma unroll
            for (int ni = 0; ni < 4; ++ni) {
                int row = wc * 64 + ni * 16 + fr;
                int sl  = (h * 4 + fq) ^ (row & 7);
                const u16* p = &lds[2][row * 64 + sl * 8];
                bh[ni] = *(const bf16x8*)p;
                bl[ni] = *(const bf16x8*)(p + 8192);
            }
            #pragma unroll
            for (int mi = 0; mi < 4; ++mi)
                #pragma unroll
                for (int ni = 0; ni < 4; ++ni) {
                    acc[mi][ni] = __builtin_amdgcn_mfma_f32_16x16x32_bf16(ah[mi], bh[ni], acc[mi][ni], 0, 0, 0);
                    acc[mi][ni] = __builtin_amdgcn_mfma_f32_16x16x32_bf16(ah[mi], bl[ni], acc[mi][ni], 0, 0, 0);
                    acc[mi][ni] = __builtin_amdgcn_mfma_f32_16x16x32_bf16(al[mi], bh[ni], acc[mi][ni], 0, 0, 0);
                }
        }
        __syncthreads();
    }

    float* Cz = C + (EPI == 0 ? (size_t)blockIdx.z * zStride : (size_t)0);
    #pragma unroll
    for (int mi = 0; mi < 4; ++mi)
        #pragma unroll
        for (int ni = 0; ni < 4; ++ni) {
            int gr = m0 + wr * 64 + mi * 16 + fq * 4;
            int gc = n0 + wc * 64 + ni * 16 + fr;
            float* cp = Cz + (size_t)gr * ldc + gc;
            #pragma unroll
            for (int r = 0; r < 4; ++r) {
                float v = acc[mi][ni][r];
                if (EPI == 1) v = softplusf(v + bias[gc]);
                if (EPI == 2) v += cp[(size_t)r * ldc];
                cp[(size_t)r * ldc] = v;
            }
        }
}

// ---------------- depthwise causal conv1d(k=4)+bias+silu -> u hi/lo ----------------
__global__ __launch_bounds__(256) void k_conv1d(
    const float* __restrict__ xz, const float* __restrict__ w,
    const float* __restrict__ bias, u16* __restrict__ uh, u16* __restrict__ ul)
{
    int idx = blockIdx.x * 256 + threadIdx.x;
    if (idx >= NB * NT * (DINNER / 4)) return;
    int dv = idx % (DINNER / 4);
    int t  = (idx / (DINNER / 4)) % NT;
    int b  = idx / ((DINNER / 4) * NT);
    int d  = dv * 4;
    const float* base = xz + ((size_t)b * NT + t) * (2 * DINNER) + d;
    float4 a[4];
    #pragma unroll
    for (int k = 0; k < 4; ++k) {
        int tm = t - 3 + k;
        if (tm >= 0) a[k] = *(const float4*)(base + (ptrdiff_t)(k - 3) * (2 * DINNER));
        else         a[k] = make_float4(0.f, 0.f, 0.f, 0.f);
    }
    float4 w0 = *(const float4*)(w + (size_t)(d + 0) * 4);
    float4 w1 = *(const float4*)(w + (size_t)(d + 1) * 4);
    float4 w2 = *(const float4*)(w + (size_t)(d + 2) * 4);
    float4 w3 = *(const float4*)(w + (size_t)(d + 3) * 4);
    float4 bb = *(const float4*)(bias + d);
    float o0 = siluf(bb.x + a[0].x * w0.x + a[1].x * w0.y + a[2].x * w0.z + a[3].x * w0.w);
    float o1 = siluf(bb.y + a[0].y * w1.x + a[1].y * w1.y + a[2].y * w1.z + a[3].y * w1.w);
    float o2 = siluf(bb.z + a[0].z * w2.x + a[1].z * w2.y + a[2].z * w2.z + a[3].z * w2.w);
    float o3 = siluf(bb.w + a[0].w * w3.x + a[1].w * w3.y + a[2].w * w3.z + a[3].w * w3.w);
    u16 h0 = f2bf(o0), h1 = f2bf(o1), h2 = f2bf(o2), h3 = f2bf(o3);
    u16 l0 = f2bf(o0 - bf2f(h0)), l1 = f2bf(o1 - bf2f(h1));
    u16 l2 = f2bf(o2 - bf2f(h2)), l3 = f2bf(o3 - bf2f(h3));
    size_t ob = ((size_t)b * NT + t) * DINNER + d;
    uint2 hv = { (u32)h0 | ((u32)h1 << 16), (u32)h2 | ((u32)h3 << 16) };
    uint2 lv = { (u32)l0 | ((u32)l1 << 16), (u32)l2 | ((u32)l3 << 16) };
    *(uint2*)(uh + ob) = hv;
    *(uint2*)(ul + ob) = lv;
}

// ---------------- reduce 4 split-K slabs of x_proj ----------------
__global__ __launch_bounds__(256) void k_reduce4(const float* __restrict__ part,
                                                 float* __restrict__ out)
{
    int idx = blockIdx.x * 256 + threadIdx.x;
    if (idx >= MROWS * 128) return;
    float s = part[idx] + part[(size_t)1 * MROWS * 128 + idx]
            + part[(size_t)2 * MROWS * 128 + idx] + part[(size_t)3 * MROWS * 128 + idx];
    out[idx] = s;
}

// ---------------- scan pass 1: per-chunk local scan (h from 0) + decay product ----------------
__global__ __launch_bounds__(256) void k_scan_p1(
    const float* __restrict__ xz, const u16* __restrict__ uh, const u16* __restrict__ ul,
    const float* __restrict__ xdbl, const float* __restrict__ A_log,
    float* __restrict__ HP, float* __restrict__ PP)
{
    const int tid = threadIdx.x;
    const int g = tid >> 3, i = tid & 7;
    const int d = blockIdx.x * 32 + g;
    const int c = blockIdx.y, b = blockIdx.z;
    const float L2E = 1.44269504088896340736f;
    float aa0 = -__expf(A_log[d * DSTATE + 2 * i    ]) * L2E;
    float aa1 = -__expf(A_log[d * DSTATE + 2 * i + 1]) * L2E;
    const int t0 = c * CHKT;
    const float* dP = xz + ((size_t)b * NT + t0) * (2 * DINNER) + d;
    const u16* uhP = uh + ((size_t)b * NT + t0) * DINNER + d;
    const u16* ulP = ul + ((size_t)b * NT + t0) * DINNER + d;
    const float* bP = xdbl + ((size_t)b * NT + t0) * 128 + DTRANK + 2 * i;
    float h0 = 0.f, h1 = 0.f, P0 = 1.f, P1 = 1.f;
    float dlt = dP[0];
    float uu = bf2f(uhP[0]) + bf2f(ulP[0]);
    float2 Bf = *(const float2*)bP;
    for (int t = 0; t < CHKT; ++t) {
        float dlt_n = 0.f, uu_n = 0.f; float2 Bn = {0.f, 0.f};
        if (t + 1 < CHKT) {
            dlt_n = dP[2 * DINNER];
            uu_n = bf2f(uhP[DINNER]) + bf2f(ulP[DINNER]);
            Bn = *(const float2*)(bP + 128);
        }
        float du = dlt * uu;
        float e0 = exp2f(dlt * aa0);
        float e1 = exp2f(dlt * aa1);
        h0 = fmaf(e0, h0, du * Bf.x);
        h1 = fmaf(e1, h1, du * Bf.y);
        P0 *= e0; P1 *= e1;
        dP += 2 * DINNER; uhP += DINNER; ulP += DINNER; bP += 128;
        dlt = dlt_n; uu = uu_n; Bf = Bn;
    }
    size_t a = (((size_t)(b * NCHK + c) * DINNER) + d) * DSTATE + 2 * i;
    HP[a] = h0; HP[a + 1] = h1;
    PP[a] = P0; PP[a + 1] = P1;
}

// ---------------- scan pass 2: chunk-prefix; HP becomes h_init per chunk ----------------
__global__ __launch_bounds__(256) void k_scan_p2(float* __restrict__ HP,
                                                 const float* __restrict__ PP)
{
    int idx = blockIdx.x * 256 + threadIdx.x;
    if (idx >= NB * DINNER * DSTATE) return;
    int b = idx / (DINNER * DSTATE);
    int ds = idx - b * (DINNER * DSTATE);
    float h = 0.f;
    #pragma unroll
    for (int c = 0; c < NCHK; ++c) {
        size_t a = (size_t)(b * NCHK + c) * (DINNER * DSTATE) + ds;
        float hc = HP[a], P = PP[a];
        HP[a] = h;                 // h_init for chunk c
        h = fmaf(P, h, hc);
    }
}

// ---------------- scan pass 3: per-chunk scan with h_init, y+gating in place ----------------
__global__ __launch_bounds__(256) void k_scan_p3(
    const float* __restrict__ xz,
    u16* uh, u16* ul,
    const float* __restrict__ xdbl,
    const float* __restrict__ A_log, const float* __restrict__ Dp,
    const float* __restrict__ HP)
{
    const int tid = threadIdx.x;
    const int g = tid >> 3, i = tid & 7;
    const int d = blockIdx.x * 32 + g;
    const int c = blockIdx.y, b = blockIdx.z;
    const float L2E = 1.44269504088896340736f;
    float aa0 = -__expf(A_log[d * DSTATE + 2 * i    ]) * L2E;
    float aa1 = -__expf(A_log[d * DSTATE + 2 * i + 1]) * L2E;
    const float dp = Dp[d];
    const int t0 = c * CHKT;
    const float* dP = xz + ((size_t)b * NT + t0) * (2 * DINNER) + d;
    const float* zP = dP + DINNER;
    const u16* uhP = uh + ((size_t)b * NT + t0) * DINNER + d;
    const u16* ulP = ul + ((size_t)b * NT + t0) * DINNER + d;
    u16* yhP = (u16*)uhP;
    u16* ylP = (u16*)ulP;
    const float* bP = xdbl + ((size_t)b * NT + t0) * 128 + DTRANK + 2 * i;
    const float* cP = bP + DSTATE;
    size_t ha = (((size_t)(b * NCHK + c) * DINNER) + d) * DSTATE + 2 * i;
    float h0 = HP[ha], h1 = HP[ha + 1];
    float dlt = dP[0], zz = zP[0];
    float uu = bf2f(uhP[0]) + bf2f(ulP[0]);
    float2 Bf = *(const float2*)bP;
    float2 Cf = *(const float2*)cP;
    for (int t = 0; t < CHKT; ++t) {
        float dlt_n = 0.f, uu_n = 0.f, zz_n = 0.f;
        float2 Bn = {0.f, 0.f}, Cn = {0.f, 0.f};
        if (t + 1 < CHKT) {
            dlt_n = dP[2 * DINNER]; zz_n = zP[2 * DINNER];
            uu_n = bf2f(uhP[DINNER]) + bf2f(ulP[DINNER]);
            Bn = *(const float2*)(bP + 128); Cn = *(const float2*)(cP + 128);
        }
        float du = dlt * uu;
        h0 = fmaf(exp2f(dlt * aa0), h0, du * Bf.x);
        h1 = fmaf(exp2f(dlt * aa1), h1, du * Bf.y);
        float p = fmaf(h0, Cf.x, h1 * Cf.y);
        p += __shfl_xor(p, 1);
        p += __shfl_xor(p, 2);
        p += __shfl_xor(p, 4);
        if (i == 0) {
            float yv = (p + uu * dp) * siluf(zz);
            u16 hh = f2bf(yv);
            yhP[0] = hh;
            ylP[0] = f2bf(yv - bf2f(hh));
        }
        dP += 2 * DINNER; zP += 2 * DINNER;
        uhP += DINNER; ulP += DINNER; yhP += DINNER; ylP += DINNER;
        bP += 128; cP += 128;
        dlt = dlt_n; zz = zz_n; uu = uu_n; Bf = Bn; Cf = Cn;
    }
}

// ---------------- final fc + silu + transpose to (B,5,T) ----------------
__global__ __launch_bounds__(256) void k_fc(const float* __restrict__ hR,
    const float* __restrict__ w, const float* __restrict__ bias,
    float* __restrict__ out)
{
    int row = blockIdx.x;
    int tid = threadIdx.x;
    const float* p = hR + (size_t)row * DMODEL;
    float acc[NCLASS] = {0.f, 0.f, 0.f, 0.f, 0.f};
    #pragma unroll
    for (int j = 0; j < 6; ++j) {
        int col = tid + j * 256;
        float v = p[col];
        #pragma unroll
        for (int c = 0; c < NCLASS; ++c)
            acc[c] = fmaf(v, w[c * DMODEL + col], acc[c]);
    }
    #pragma unroll
    for (int c = 0; c < NCLASS; ++c)
        #pragma unroll
        for (int off = 1; off < 64; off <<= 1)
            acc[c] += __shfl_xor(acc[c], off);
    __shared__ float red[4][NCLASS];
    int lane = tid & 63, wv = tid >> 6;
    if (lane == 0)
        for (int c = 0; c < NCLASS; ++c) red[wv][c] = acc[c];
    __syncthreads();
    if (tid < NCLASS) {
        float s = red[0][tid] + red[1][tid] + red[2][tid] + red[3][tid] + bias[tid];
        int b = row >> 10, t = row & (NT - 1);
        out[((size_t)b * NCLASS + tid) * NT + t] = siluf(s);
    }
}

extern "C" void kernel_launch(void* const* d_in, const int* in_sizes, int n_in,
                              void* d_out, int out_size, void* d_ws, size_t ws_size,
                              hipStream_t stream)
{
    const float* x      = (const float*)d_in[0];
    const float* c1a_w  = (const float*)d_in[1];
    const float* c1a_b  = (const float*)d_in[2];
    const float* c1b_w  = (const float*)d_in[3];
    const float* c1b_b  = (const float*)d_in[4];
    const float* c1s_w  = (const float*)d_in[5];
    const float* c1s_b  = (const float*)d_in[6];
    const float* c2a_w  = (const float*)d_in[7];
    const float* c2a_b  = (const float*)d_in[8];
    const float* c2b_w  = (const float*)d_in[9];
    const float* c2b_b  = (const float*)d_in[10];
    const float* norm_w = (const float*)d_in[11];
    const float* in_w   = (const float*)d_in[12];
    const float* conv_w = (const float*)d_in[13];
    const float* conv_b = (const float*)d_in[14];
    const float* xproj_w= (const float*)d_in[15];
    const float* dt_w   = (const float*)d_in[16];
    const float* dt_b   = (const float*)d_in[17];
    const float* A_log  = (const float*)d_in[18];
    const float* Dp     = (const float*)d_in[19];
    const float* out_w  = (const float*)d_in[20];
    const float* fc_w   = (const float*)d_in[21];
    const float* fc_b   = (const float*)d_in[22];
    float* outp = (float*)d_out;
    (void)in_sizes; (void)n_in; (void)out_size; (void)ws_size;

    char* base = (char*)d_ws;
    size_t off = 0;
    auto takeB = [&](size_t bytes) { void* p = base + off; off = (off + bytes + 255) & ~(size_t)255; return p; };
    float* HCAT = (float*)takeB((size_t)NB * NDIM * NT * 4);
    float* XZ   = (float*)takeB((size_t)MROWS * 2 * DINNER * 4);
    float* RES  = (float*)takeB((size_t)MROWS * DMODEL * 4);
    u16*   XNh  = (u16*)takeB((size_t)MROWS * DMODEL * 2);
    u16*   XNl  = (u16*)takeB((size_t)MROWS * DMODEL * 2);
    u16*   Uh   = (u16*)takeB((size_t)MROWS * DINNER * 2);
    u16*   Ul   = (u16*)takeB((size_t)MROWS * DINNER * 2);
    float* XDBL = (float*)takeB((size_t)MROWS * 128 * 4);
    float* XPART= (float*)takeB((size_t)4 * MROWS * 128 * 4);
    u16*   XDh  = (u16*)takeB((size_t)MROWS * 128 * 2);
    u16*   XDl  = (u16*)takeB((size_t)MROWS * 128 * 2);
    u16*   Wh   = (u16*)takeB((size_t)9437184 * 2);
    u16*   Wl   = (u16*)takeB((size_t)9437184 * 2);
    float* HP   = (float*)takeB((size_t)NB * DINNER * DSTATE * NCHK * 4);  // 12.6 MB
    float* PP   = (float*)takeB((size_t)NB * DINNER * DSTATE * NCHK * 4);  // 12.6 MB
    u16*   CW1h = (u16*)takeB(18432);
    u16*   CW1l = (u16*)takeB(18432);
    u16*   CW2h = (u16*)takeB(18432);
    u16*   CW2l = (u16*)takeB(18432);
    u16*   CW3h = (u16*)takeB(18432);
    u16*   CW3l = (u16*)takeB(18432);
    u16*   ZPAD = (u16*)takeB(256);

    u16* T1h = (u16*)XZ;
    u16* T1l = T1h + (size_t)NB * NDIM * NT * 32;
    u16* T3h = (u16*)XZ;
    u16* T3l = T3h + (size_t)NB * NDIM * NT * 32;
    u16* P1h = Uh;
    u16* P1l = Ul;

    const int n1 = NB * NDIM * NT;
    k_zero<<<1, 128, 0, stream>>>(ZPAD);
    k_prep  <<<(n1 + 255) / 256, 256, 0, stream>>>(x, HCAT);
    k_wconv<<<36, 256, 0, stream>>>(c1b_w, CW1h, CW1l);
    k_wconv<<<36, 256, 0, stream>>>(c2a_w, CW2h, CW2l);
    k_wconv<<<36, 256, 0, stream>>>(c2b_w, CW3h, CW3l);
    k_conv1a<<<(n1 + 255) / 256, 256, 0, stream>>>(HCAT, c1a_w, c1a_b, T1h, T1l);
    k_convmfma<0><<<dim3(16, 96, NB), 256, 0, stream>>>(
        T1h, T1l, CW1h, CW1l, HCAT, c1s_w, c1s_b, nullptr, nullptr,
        c1b_b, P1h, P1l, nullptr, ZPAD);
    k_convmfma<1><<<dim3(16, 48, NB), 256, 0, stream>>>(
        P1h, P1l, CW2h, CW2l, nullptr, nullptr, nullptr, nullptr, nullptr,
        c2a_b, T3h, T3l, nullptr, ZPAD);
    k_convmfma<2><<<dim3(16, 48, NB), 256, 0, stream>>>(
        T3h, T3l, CW3h, CW3l, nullptr, nullptr, nullptr, P1h, P1l,
        c2b_b, nullptr, nullptr, RES, ZPAD);

    for (int l = 0; l < NLAYER; ++l) {
        k_rmsnorm<<<MROWS, 256, 0, stream>>>(RES, norm_w + (size_t)l * DMODEL, XNh, XNl);
        k_split<<<(9437184 / 4 + 255) / 256, 256, 0, stream>>>(
            in_w + (size_t)l * 2 * DINNER * DMODEL, Wh, Wl, 9437184 / 4);
        k_gemm_mfma<0><<<dim3(2 * DINNER / 128, MROWS / 128, 1), 256, 0, stream>>>(
            XNh, XNl, DMODEL, Wh, Wl, DMODEL, XZ, 2 * DINNER, DMODEL, nullptr, 0);
        k_conv1d<<<(NB * NT * (DINNER / 4) + 255) / 256, 256, 0, stream>>>(
            XZ, conv_w + (size_t)l * DINNER * 4, conv_b + (size_t)l * DINNER, Uh, Ul);
        k_split<<<(393216 / 4 + 255) / 256, 256, 0, stream>>>(
            xproj_w + (size_t)l * 128 * DINNER, Wh, Wl, 393216 / 4);
        k_gemm_mfma<0><<<dim3(1, MROWS / 128, 4), 256, 0, stream>>>(
            Uh, Ul, DINNER, Wh, Wl, DINNER, XPART, 128, DINNER, nullptr, (size_t)MROWS * 128);
        k_reduce4<<<(MROWS * 128 + 255) / 256, 256, 0, stream>>>(XPART, XDBL);
        k_split<<<(MROWS * 128 / 4 + 255) / 256, 256, 0, stream>>>(XDBL, XDh, XDl, MROWS * 128 / 4);
        k_wsplit_pad<<<(DINNER * 128 + 255) / 256, 256, 0, stream>>>(
            dt_w + (size_t)l * DINNER * DTRANK, Wh, Wl);
        k_gemm_mfma<1><<<dim3(DINNER / 128, MROWS / 128, 1), 256, 0, stream>>>(
            XDh, XDl, 128, Wh, Wl, 128, XZ, 2 * DINNER, 128,
            dt_b + (size_t)l * DINNER, 0);
        k_scan_p1<<<dim3(DINNER / 32, NCHK, NB), 256, 0, stream>>>(
            XZ, Uh, Ul, XDBL, A_log + (size_t)l * DINNER * DSTATE, HP, PP);
        k_scan_p2<<<(NB * DINNER * DSTATE + 255) / 256, 256, 0, stream>>>(HP, PP);
        k_scan_p3<<<dim3(DINNER / 32, NCHK, NB), 256, 0, stream>>>(
            XZ, Uh, Ul, XDBL, A_log + (size_t)l * DINNER * DSTATE,
            Dp + (size_t)l * DINNER, HP);
        k_split<<<(4718592 / 4 + 255) / 256, 256, 0, stream>>>(
            out_w + (size_t)l * DMODEL * DINNER, Wh, Wl, 4718592 / 4);
        k_gemm_mfma<2><<<dim3(DMODEL / 128, MROWS / 128, 1), 256, 0, stream>>>(
            Uh, Ul, DINNER, Wh, Wl, DINNER, RES, DMODEL, DINNER, nullptr, 0);
    }
    k_fc<<<MROWS, 256, 0, stream>>>(RES, fc_w, fc_b, outp);
}

// Round 5
// 5223.568 us; speedup vs baseline: 3.5600x; 1.2480x over previous
//
#include <hip/hip_runtime.h>
#include <cstdint>
#include <cstddef>

#define DEV static __device__ __forceinline__

typedef unsigned short u16;
typedef unsigned int   u32;
typedef __bf16 bf16x8 __attribute__((ext_vector_type(8)));
typedef float  f32x4  __attribute__((ext_vector_type(4)));

namespace {
constexpr int NB     = 8;
constexpr int NT     = 1024;
constexpr int NMEL   = 96;
constexpr int NDIM   = 192;
constexpr int NCH    = 32;
constexpr int DMODEL = 1536;
constexpr int DINNER = 3072;
constexpr int DSTATE = 16;
constexpr int DTRANK = 96;
constexpr int NLAYER = 4;
constexpr int NCLASS = 5;
constexpr int MROWS  = NB * NT;   // 8192
constexpr int NCHK   = 16;
constexpr int CHKT   = NT / NCHK; // 64
}

DEV float siluf(float x)    { return x / (1.0f + __expf(-x)); }
DEV float softplusf(float x){ return fmaxf(x, 0.0f) + log1pf(__expf(-fabsf(x))); }

DEV u16 f2bf(float f) {
    u32 u = __float_as_uint(f);
    u32 r = u + 0x7FFFu + ((u >> 16) & 1u);
    return (u16)(r >> 16);
}
DEV float bf2f(u16 h) { return __uint_as_float(((u32)h) << 16); }

#define GLD(gp, lp) __builtin_amdgcn_global_load_lds( \
    (const __attribute__((address_space(1))) u32*)(const void*)(gp), \
    (__attribute__((address_space(3))) u32*)(void*)(lp), 16, 0, 0)

// ---------------- zero pad buffer ----------------
__global__ void k_zero(u16* p) { p[threadIdx.x] = 0; }

// ---------------- prep: x -> hcat (B,192,T): [x ; relu(diff)] ----------------
__global__ __launch_bounds__(256) void k_prep(const float* __restrict__ x,
                                              float* __restrict__ hcat)
{
    int idx = blockIdx.x * 256 + threadIdx.x;
    if (idx >= NB * NDIM * NT) return;
    int t = idx & (NT - 1);
    int m = (idx >> 10) % NDIM;
    int b = idx / (NDIM * NT);
    float v;
    if (m < NMEL) {
        v = x[((size_t)b * NMEL + m) * NT + t];
    } else {
        int mm = m - NMEL;
        v = 0.f;
        if (t > 0) {
            const float* p = x + ((size_t)b * NMEL + mm) * NT + t;
            v = fmaxf(p[0] - p[-1], 0.f);
        }
    }
    hcat[idx] = v;
}

// ---------------- conv weight prep: (32,32,3,3) -> [tap][cout][ci] hi/lo ----------------
__global__ __launch_bounds__(256) void k_wconv(const float* __restrict__ w,
    u16* __restrict__ dh, u16* __restrict__ dl)
{
    int idx = blockIdx.x * 256 + threadIdx.x;
    if (idx >= 9216) return;
    int ci = idx & 31, cout = (idx >> 5) & 31, tap = idx >> 10;
    float v = w[((size_t)cout * 32 + ci) * 9 + tap];
    u16 h = f2bf(v);
    dh[idx] = h;
    dl[idx] = f2bf(v - bf2f(h));
}

// ---------------- conv1a (1->32, 3x3) + silu -> NHWC bf16 hi/lo ----------------
__global__ __launch_bounds__(256) void k_conv1a(const float* __restrict__ hcat,
    const float* __restrict__ w, const float* __restrict__ bias,
    u16* __restrict__ oh, u16* __restrict__ ol)   // (B,192,T,32)
{
    int idx = blockIdx.x * 256 + threadIdx.x;
    if (idx >= NB * NDIM * NT) return;
    int t = idx & (NT - 1);
    int h = (idx >> 10) % NDIM;
    int b = idx / (NDIM * NT);
    float in[3][3];
    #pragma unroll
    for (int dh = 0; dh < 3; ++dh)
        #pragma unroll
        for (int dw = 0; dw < 3; ++dw) {
            int hh = h + dh - 1, tt = t + dw - 1;
            in[dh][dw] = (hh >= 0 && hh < NDIM && tt >= 0 && tt < NT)
                       ? hcat[((size_t)b * NDIM + hh) * NT + tt] : 0.f;
        }
    u16 hb[32], lb[32];
    #pragma unroll
    for (int c = 0; c < NCH; ++c) {
        float acc = bias[c];
        #pragma unroll
        for (int dh = 0; dh < 3; ++dh)
            #pragma unroll
            for (int dw = 0; dw < 3; ++dw)
                acc = fmaf(in[dh][dw], w[c * 9 + dh * 3 + dw], acc);
        float o = siluf(acc);
        u16 hh2 = f2bf(o);
        hb[c] = hh2;
        lb[c] = f2bf(o - bf2f(hh2));
    }
    size_t ob = (((size_t)b * NDIM + h) * NT + t) * 32;
    #pragma unroll
    for (int j = 0; j < 8; ++j) {
        ushort4 hv = { hb[j*4], hb[j*4+1], hb[j*4+2], hb[j*4+3] };
        ushort4 lv = { lb[j*4], lb[j*4+1], lb[j*4+2], lb[j*4+3] };
        *(ushort4*)(oh + ob + j * 4) = hv;
        *(ushort4*)(ol + ob + j * 4) = lv;
    }
}

// ---------------- MFMA implicit-GEMM conv 32->32 3x3 (NHWC bf16 hi/lo) ----------------
template<int VAR>
__global__ __launch_bounds__(256) void k_convmfma(
    const u16* __restrict__ Xh, const u16* __restrict__ Xl,
    const u16* __restrict__ CWh, const u16* __restrict__ CWl,
    const float* __restrict__ hcat, const float* __restrict__ sw, const float* __restrict__ sb,
    const u16* __restrict__ Sh, const u16* __restrict__ Sl,
    const float* __restrict__ bias,
    u16* __restrict__ Oh, u16* __restrict__ Ol,
    float* __restrict__ RES,
    const u16* __restrict__ zeropad)
{
    constexpr int HIN = (VAR == 0) ? 192 : 96;
    __shared__ __align__(16) u16 lds[2][8448];
    const int t0 = blockIdx.x * 64;
    const int ho = blockIdx.y;
    const int b  = blockIdx.z;
    const int tid = threadIdx.x;
    const int wid = tid >> 6, lane = tid & 63;
    const int r0 = 2 * ho - 1;

    for (int cb = wid * 64; cb < 2112; cb += 256) {
        int c = cb + lane;
        int plane = (c >= 1056) ? 1 : 0;
        int cc = c - plane * 1056;
        int row = cc / 264;
        int rc  = cc - row * 264;
        int pos = rc >> 2;
        int slot = rc & 3;
        int cib = slot ^ ((pos >> 1) & 3);
        int h = r0 + row;
        int t = t0 - 1 + pos;
        const u16* bp = plane ? Xl : Xh;
        const u16* src = (h >= 0 && h < HIN && t >= 0 && t < NT)
            ? bp + (((size_t)(b * HIN + h)) * NT + t) * 32 + cib * 8
            : zeropad;
        u16* ldst = &lds[0][0] + (size_t)cb * 8;
        GLD(src, ldst);
    }
    __syncthreads();

    const int fr = lane & 15, fq = lane >> 4;
    f32x4 acc[2][2];
    #pragma unroll
    for (int pr = 0; pr < 2; ++pr)
        #pragma unroll
        for (int mt = 0; mt < 2; ++mt) acc[pr][mt] = (f32x4){0.f, 0.f, 0.f, 0.f};

    #pragma unroll
    for (int dh = 0; dh < 3; ++dh) {
        #pragma unroll
        for (int dt = 0; dt < 3; ++dt) {
            int tap = dh * 3 + dt;
            bf16x8 wh[2], wl[2];
            #pragma unroll
            for (int mt = 0; mt < 2; ++mt) {
                size_t wo = ((size_t)tap * 32 + mt * 16 + fr) * 32 + fq * 8;
                wh[mt] = *(const bf16x8*)(CWh + wo);
                wl[mt] = *(const bf16x8*)(CWl + wo);
            }
            int p = (wid << 4) + fr + dt;
            int sl = fq ^ ((p >> 1) & 3);
            #pragma unroll
            for (int pr = 0; pr < 2; ++pr) {
                int rr = pr + dh;
                const u16* lp = &lds[0][0] + ((rr * 66 + p) * 4 + sl) * 8;
                bf16x8 xh = *(const bf16x8*)lp;
                bf16x8 xl = *(const bf16x8*)(lp + 8448);
                #pragma unroll
                for (int mt = 0; mt < 2; ++mt) {
                    acc[pr][mt] = __builtin_amdgcn_mfma_f32_16x16x32_bf16(wh[mt], xh, acc[pr][mt], 0, 0, 0);
                    acc[pr][mt] = __builtin_amdgcn_mfma_f32_16x16x32_bf16(wh[mt], xl, acc[pr][mt], 0, 0, 0);
                    acc[pr][mt] = __builtin_amdgcn_mfma_f32_16x16x32_bf16(wl[mt], xh, acc[pr][mt], 0, 0, 0);
                }
            }
        }
    }

    const int t = t0 + (wid << 4) + fr;
    float hc0 = 0.f, hc1 = 0.f;
    if (VAR == 0) {
        hc0 = hcat[((size_t)(b * NDIM + 2 * ho    )) * NT + t];
        hc1 = hcat[((size_t)(b * NDIM + 2 * ho + 1)) * NT + t];
    }
    #pragma unroll
    for (int mt = 0; mt < 2; ++mt) {
        float v0[4], v1[4];
        if (VAR == 2) {
            ushort4 s0h = *(const ushort4*)(Sh + (((size_t)(b * 96 + 2 * ho    )) * NT + t) * 32 + mt * 16 + fq * 4);
            ushort4 s0l = *(const ushort4*)(Sl + (((size_t)(b * 96 + 2 * ho    )) * NT + t) * 32 + mt * 16 + fq * 4);
            ushort4 s1h = *(const ushort4*)(Sh + (((size_t)(b * 96 + 2 * ho + 1)) * NT + t) * 32 + mt * 16 + fq * 4);
            ushort4 s1l = *(const ushort4*)(Sl + (((size_t)(b * 96 + 2 * ho + 1)) * NT + t) * 32 + mt * 16 + fq * 4);
            v0[0] = bf2f(s0h.x) + bf2f(s0l.x); v0[1] = bf2f(s0h.y) + bf2f(s0l.y);
            v0[2] = bf2f(s0h.z) + bf2f(s0l.z); v0[3] = bf2f(s0h.w) + bf2f(s0l.w);
            v1[0] = bf2f(s1h.x) + bf2f(s1l.x); v1[1] = bf2f(s1h.y) + bf2f(s1l.y);
            v1[2] = bf2f(s1h.z) + bf2f(s1l.z); v1[3] = bf2f(s1h.w) + bf2f(s1l.w);
        }
        u16 hs[4], ls[4];
        float r0v[4], r1v[4];
        #pragma unroll
        for (int r = 0; r < 4; ++r) {
            int c = mt * 16 + fq * 4 + r;
            float a0 = acc[0][mt][r] + bias[c];
            float a1 = acc[1][mt][r] + bias[c];
            if (VAR == 0) {
                a0 += fmaf(hc0, sw[c], sb[c]);
                a1 += fmaf(hc1, sw[c], sb[c]);
            }
            if (VAR == 2) { a0 += v0[r]; a1 += v1[r]; }
            a0 = siluf(a0); a1 = siluf(a1);
            if (VAR == 1) { r0v[r] = a0; r1v[r] = a1; }
            else {
                float m = fmaxf(a0, a1);
                if (VAR == 2) r0v[r] = m;
                else { u16 hh = f2bf(m); hs[r] = hh; ls[r] = f2bf(m - bf2f(hh)); }
            }
        }
        if (VAR == 0) {
            size_t ob = (((size_t)(b * 96 + ho)) * NT + t) * 32 + mt * 16 + fq * 4;
            ushort4 hv = { hs[0], hs[1], hs[2], hs[3] };
            ushort4 lv = { ls[0], ls[1], ls[2], ls[3] };
            *(ushort4*)(Oh + ob) = hv;
            *(ushort4*)(Ol + ob) = lv;
        } else if (VAR == 1) {
            #pragma unroll
            for (int pr = 0; pr < 2; ++pr) {
                size_t ob = (((size_t)(b * 96 + 2 * ho + pr)) * NT + t) * 32 + mt * 16 + fq * 4;
                u16 hh[4], ll[4];
                #pragma unroll
                for (int r = 0; r < 4; ++r) {
                    float m = pr ? r1v[r] : r0v[r];
                    hh[r] = f2bf(m); ll[r] = f2bf(m - bf2f(hh[r]));
                }
                ushort4 hv = { hh[0], hh[1], hh[2], hh[3] };
                ushort4 lv = { ll[0], ll[1], ll[2], ll[3] };
                *(ushort4*)(Oh + ob) = hv;
                *(ushort4*)(Ol + ob) = lv;
            }
        } else {
            #pragma unroll
            for (int r = 0; r < 4; ++r) {
                int c = mt * 16 + fq * 4 + r;
                RES[((size_t)b * NT + t) * DMODEL + c * 48 + ho] = r0v[r];
            }
        }
    }
}

// ---------------- rmsnorm over D_MODEL -> bf16 hi/lo planes ----------------
__global__ __launch_bounds__(256) void k_rmsnorm(const float* __restrict__ in,
    const float* __restrict__ w, u16* __restrict__ oh, u16* __restrict__ ol)
{
    int row = blockIdx.x;
    int tid = threadIdx.x;
    const float* p = in + (size_t)row * DMODEL;
    float v[6]; float ss = 0.f;
    #pragma unroll
    for (int j = 0; j < 6; ++j) { v[j] = p[tid + j * 256]; ss = fmaf(v[j], v[j], ss); }
    #pragma unroll
    for (int off = 1; off < 64; off <<= 1) ss += __shfl_xor(ss, off);
    __shared__ float red[4];
    int lane = tid & 63, wv = tid >> 6;
    if (lane == 0) red[wv] = ss;
    __syncthreads();
    float tot = red[0] + red[1] + red[2] + red[3];
    float sc = rsqrtf(tot * (1.0f / DMODEL) + 1e-5f);
    #pragma unroll
    for (int j = 0; j < 6; ++j) {
        int col = tid + j * 256;
        float xv = v[j] * sc * w[col];
        u16 h = f2bf(xv);
        oh[(size_t)row * DMODEL + col] = h;
        ol[(size_t)row * DMODEL + col] = f2bf(xv - bf2f(h));
    }
}

// ---------------- split fp32 -> bf16 hi/lo (n divisible by 4) ----------------
__global__ __launch_bounds__(256) void k_split(const float* __restrict__ src,
    u16* __restrict__ dh, u16* __restrict__ dl, int n4)
{
    int idx = blockIdx.x * 256 + threadIdx.x;
    if (idx >= n4) return;
    float4 v = ((const float4*)src)[idx];
    u16 h0 = f2bf(v.x), h1 = f2bf(v.y), h2 = f2bf(v.z), h3 = f2bf(v.w);
    u16 l0 = f2bf(v.x - bf2f(h0)), l1 = f2bf(v.y - bf2f(h1));
    u16 l2 = f2bf(v.z - bf2f(h2)), l3 = f2bf(v.w - bf2f(h3));
    uint2 hv = { (u32)h0 | ((u32)h1 << 16), (u32)h2 | ((u32)h3 << 16) };
    uint2 lv = { (u32)l0 | ((u32)l1 << 16), (u32)l2 | ((u32)l3 << 16) };
    ((uint2*)dh)[idx] = hv;
    ((uint2*)dl)[idx] = lv;
}

// ---------------- split dt_w [3072][96] -> padded [3072][128] hi/lo ----------------
__global__ __launch_bounds__(256) void k_wsplit_pad(const float* __restrict__ src,
    u16* __restrict__ dh, u16* __restrict__ dl)
{
    int idx = blockIdx.x * 256 + threadIdx.x;
    if (idx >= DINNER * 128) return;
    int col = idx & 127, row = idx >> 7;
    float v = (col < DTRANK) ? src[(size_t)row * DTRANK + col] : 0.f;
    u16 h = f2bf(v);
    dh[idx] = h;
    dl[idx] = f2bf(v - bf2f(h));
}

// ---------------- MFMA GEMM: C[M,N] = A[M,K] * B[N,K]^T, 3-product bf16 ----------------
template<int EPI>
__global__ __launch_bounds__(256) void k_gemm_mfma(
    const u16* __restrict__ Ahi, const u16* __restrict__ Alo, int lda,
    const u16* __restrict__ Bhi, const u16* __restrict__ Blo, int ldb,
    float* __restrict__ C, int ldc, int Ktot,
    const float* __restrict__ bias, size_t zStride)
{
    __shared__ __align__(16) u16 lds[4][8192];
    const int tid = threadIdx.x;
    const int m0 = blockIdx.y * 128, n0 = blockIdx.x * 128;
    const int kPer = Ktot / gridDim.z;
    const int kBase = blockIdx.z * kPer;
    const int wid = tid >> 6, lane = tid & 63;
    const int wr = wid >> 1, wc = wid & 1;
    const int fr = lane & 15, fq = lane >> 4;
    const int srow  = tid >> 3;
    const int sslot = (tid & 7) ^ ((tid >> 3) & 7);

    f32x4 acc[4][4];
    #pragma unroll
    for (int mi = 0; mi < 4; ++mi)
        #pragma unroll
        for (int ni = 0; ni < 4; ++ni) acc[mi][ni] = (f32x4){0.f, 0.f, 0.f, 0.f};

    for (int k0 = kBase; k0 < kBase + kPer; k0 += 64) {
        #pragma unroll
        for (int i = 0; i < 4; ++i) {
            int row = i * 32 + srow;
            size_t offA = (size_t)(m0 + row) * lda + k0 + sslot * 8;
            size_t offB = (size_t)(n0 + row) * ldb + k0 + sslot * 8;
            u16* lb = &lds[0][0] + i * 2048 + (wid << 9);
            GLD(Ahi + offA, lb);
            GLD(Alo + offA, lb + 8192);
            GLD(Bhi + offB, lb + 16384);
            GLD(Blo + offB, lb + 24576);
        }
        __syncthreads();
        #pragma unroll
        for (int h = 0; h < 2; ++h) {
            bf16x8 ah[4], al[4], bh[4], bl[4];
            #pragma unroll
            for (int mi = 0; mi < 4; ++mi) {
                int row = wr * 64 + mi * 16 + fr;
                int sl  = (h * 4 + fq) ^ (row & 7);
                const u16* p = &lds[0][row * 64 + sl * 8];
                ah[mi] = *(const bf16x8*)p;
                al[mi] = *(const bf16x8*)(p + 8192);
            }
            #pragma unroll
            for (int ni = 0; ni < 4; ++ni) {
                int row = wc * 64 + ni * 16 + fr;
                int sl  = (h * 4 + fq) ^ (row & 7);
                const u16* p = &lds[2][row * 64 + sl * 8];
                bh[ni] = *(const bf16x8*)p;
                bl[ni] = *(const bf16x8*)(p + 8192);
            }
            #pragma unroll
            for (int mi = 0; mi < 4; ++mi)
                #pragma unroll
                for (int ni = 0; ni < 4; ++ni) {
                    acc[mi][ni] = __builtin_amdgcn_mfma_f32_16x16x32_bf16(ah[mi], bh[ni], acc[mi][ni], 0, 0, 0);
                    acc[mi][ni] = __builtin_amdgcn_mfma_f32_16x16x32_bf16(ah[mi], bl[ni], acc[mi][ni], 0, 0, 0);
                    acc[mi][ni] = __builtin_amdgcn_mfma_f32_16x16x32_bf16(al[mi], bh[ni], acc[mi][ni], 0, 0, 0);
                }
        }
        __syncthreads();
    }

    float* Cz = C + (EPI == 0 ? (size_t)blockIdx.z * zStride : (size_t)0);
    #pragma unroll
    for (int mi = 0; mi < 4; ++mi)
        #pragma unroll
        for (int ni = 0; ni < 4; ++ni) {
            int gr = m0 + wr * 64 + mi * 16 + fq * 4;
            int gc = n0 + wc * 64 + ni * 16 + fr;
            float* cp = Cz + (size_t)gr * ldc + gc;
            #pragma unroll
            for (int r = 0; r < 4; ++r) {
                float v = acc[mi][ni][r];
                if (EPI == 1) v = softplusf(v + bias[gc]);
                if (EPI == 2) v += cp[(size_t)r * ldc];
                cp[(size_t)r * ldc] = v;
            }
        }
}

// ---------------- depthwise causal conv1d(k=4)+bias+silu -> u hi/lo ----------------
__global__ __launch_bounds__(256) void k_conv1d(
    const float* __restrict__ xz, const float* __restrict__ w,
    const float* __restrict__ bias, u16* __restrict__ uh, u16* __restrict__ ul)
{
    int idx = blockIdx.x * 256 + threadIdx.x;
    if (idx >= NB * NT * (DINNER / 4)) return;
    int dv = idx % (DINNER / 4);
    int t  = (idx / (DINNER / 4)) % NT;
    int b  = idx / ((DINNER / 4) * NT);
    int d  = dv * 4;
    const float* base = xz + ((size_t)b * NT + t) * (2 * DINNER) + d;
    float4 a[4];
    #pragma unroll
    for (int k = 0; k < 4; ++k) {
        int tm = t - 3 + k;
        if (tm >= 0) a[k] = *(const float4*)(base + (ptrdiff_t)(k - 3) * (2 * DINNER));
        else         a[k] = make_float4(0.f, 0.f, 0.f, 0.f);
    }
    float4 w0 = *(const float4*)(w + (size_t)(d + 0) * 4);
    float4 w1 = *(const float4*)(w + (size_t)(d + 1) * 4);
    float4 w2 = *(const float4*)(w + (size_t)(d + 2) * 4);
    float4 w3 = *(const float4*)(w + (size_t)(d + 3) * 4);
    float4 bb = *(const float4*)(bias + d);
    float o0 = siluf(bb.x + a[0].x * w0.x + a[1].x * w0.y + a[2].x * w0.z + a[3].x * w0.w);
    float o1 = siluf(bb.y + a[0].y * w1.x + a[1].y * w1.y + a[2].y * w1.z + a[3].y * w1.w);
    float o2 = siluf(bb.z + a[0].z * w2.x + a[1].z * w2.y + a[2].z * w2.z + a[3].z * w2.w);
    float o3 = siluf(bb.w + a[0].w * w3.x + a[1].w * w3.y + a[2].w * w3.z + a[3].w * w3.w);
    u16 h0 = f2bf(o0), h1 = f2bf(o1), h2 = f2bf(o2), h3 = f2bf(o3);
    u16 l0 = f2bf(o0 - bf2f(h0)), l1 = f2bf(o1 - bf2f(h1));
    u16 l2 = f2bf(o2 - bf2f(h2)), l3 = f2bf(o3 - bf2f(h3));
    size_t ob = ((size_t)b * NT + t) * DINNER + d;
    uint2 hv = { (u32)h0 | ((u32)h1 << 16), (u32)h2 | ((u32)h3 << 16) };
    uint2 lv = { (u32)l0 | ((u32)l1 << 16), (u32)l2 | ((u32)l3 << 16) };
    *(uint2*)(uh + ob) = hv;
    *(uint2*)(ul + ob) = lv;
}

// ---------------- reduce 4 split-K slabs of x_proj ----------------
__global__ __launch_bounds__(256) void k_reduce4(const float* __restrict__ part,
                                                 float* __restrict__ out)
{
    int idx = blockIdx.x * 256 + threadIdx.x;
    if (idx >= MROWS * 128) return;
    float s = part[idx] + part[(size_t)1 * MROWS * 128 + idx]
            + part[(size_t)2 * MROWS * 128 + idx] + part[(size_t)3 * MROWS * 128 + idx];
    out[idx] = s;
}

// ---------------- scan pass 1: lane-per-d local chunk scan; h_final + sum(delta) ----------------
__global__ __launch_bounds__(256) void k_scan_p1(
    const float* __restrict__ xz, const u16* __restrict__ uh, const u16* __restrict__ ul,
    const float* __restrict__ xdbl, const float* __restrict__ A_log,
    float* __restrict__ HP, float* __restrict__ SS)
{
    const int d = blockIdx.x * 256 + threadIdx.x;
    const int c = blockIdx.y, b = blockIdx.z;
    const float L2E = 1.44269504088896340736f;
    float aa[DSTATE];
    #pragma unroll
    for (int s = 0; s < DSTATE; ++s)
        aa[s] = -__expf(A_log[d * DSTATE + s]) * L2E;
    const int t0 = c * CHKT;
    const float* dP = xz + ((size_t)b * NT + t0) * (2 * DINNER) + d;
    const u16* uhP = uh + ((size_t)b * NT + t0) * DINNER + d;
    const u16* ulP = ul + ((size_t)b * NT + t0) * DINNER + d;
    const float* bP = xdbl + ((size_t)b * NT + t0) * 128 + DTRANK;
    float h[DSTATE];
    #pragma unroll
    for (int s = 0; s < DSTATE; ++s) h[s] = 0.f;
    float S = 0.f;
    float dlt = dP[0];
    float uu = bf2f(uhP[0]) + bf2f(ulP[0]);
    float Bv[DSTATE];
    #pragma unroll
    for (int j = 0; j < 4; ++j) *(f32x4*)&Bv[j * 4] = *(const f32x4*)(bP + j * 4);
    for (int t = 0; t < CHKT; ++t) {
        float dlt_n = 0.f, uu_n = 0.f;
        float Bn[DSTATE];
        #pragma unroll
        for (int s = 0; s < DSTATE; ++s) Bn[s] = 0.f;
        if (t + 1 < CHKT) {
            dlt_n = dP[2 * DINNER];
            uu_n = bf2f(uhP[DINNER]) + bf2f(ulP[DINNER]);
            #pragma unroll
            for (int j = 0; j < 4; ++j) *(f32x4*)&Bn[j * 4] = *(const f32x4*)(bP + 128 + j * 4);
        }
        float du = dlt * uu;
        S += dlt;
        #pragma unroll
        for (int s = 0; s < DSTATE; ++s) {
            float e = exp2f(dlt * aa[s]);
            h[s] = fmaf(e, h[s], du * Bv[s]);
        }
        dP += 2 * DINNER; uhP += DINNER; ulP += DINNER; bP += 128;
        dlt = dlt_n; uu = uu_n;
        #pragma unroll
        for (int s = 0; s < DSTATE; ++s) Bv[s] = Bn[s];
    }
    size_t a = (((size_t)(b * NCHK + c) * DINNER) + d) * DSTATE;
    #pragma unroll
    for (int j = 0; j < 4; ++j) *(f32x4*)(HP + a + j * 4) = *(const f32x4*)&h[j * 4];
    SS[(size_t)(b * NCHK + c) * DINNER + d] = S;
}

// ---------------- scan pass 2: chunk-prefix; HP becomes h_init per chunk ----------------
__global__ __launch_bounds__(256) void k_scan_p2(float* __restrict__ HP,
    const float* __restrict__ SS, const float* __restrict__ A_log)
{
    int idx = blockIdx.x * 256 + threadIdx.x;
    if (idx >= NB * DINNER * DSTATE) return;
    int s = idx & (DSTATE - 1);
    int d = (idx >> 4) % DINNER;
    int b = idx / (DINNER * DSTATE);
    const float L2E = 1.44269504088896340736f;
    float aa = -__expf(A_log[d * DSTATE + s]) * L2E;
    float h = 0.f;
    #pragma unroll
    for (int c = 0; c < NCHK; ++c) {
        size_t a = (((size_t)(b * NCHK + c) * DINNER) + d) * DSTATE + s;
        float hc = HP[a];
        float P = exp2f(aa * SS[(size_t)(b * NCHK + c) * DINNER + d]);
        HP[a] = h;
        h = fmaf(P, h, hc);
    }
}

// ---------------- scan pass 3: lane-per-d chunk scan with h_init; y+gating in place ----------------
__global__ __launch_bounds__(256) void k_scan_p3(
    const float* __restrict__ xz,
    u16* uh, u16* ul,
    const float* __restrict__ xdbl,
    const float* __restrict__ A_log, const float* __restrict__ Dp,
    const float* __restrict__ HP)
{
    const int d = blockIdx.x * 256 + threadIdx.x;
    const int c = blockIdx.y, b = blockIdx.z;
    const float L2E = 1.44269504088896340736f;
    float aa[DSTATE];
    #pragma unroll
    for (int s = 0; s < DSTATE; ++s)
        aa[s] = -__expf(A_log[d * DSTATE + s]) * L2E;
    const float dp = Dp[d];
    const int t0 = c * CHKT;
    const float* dP = xz + ((size_t)b * NT + t0) * (2 * DINNER) + d;
    const float* zP = dP + DINNER;
    const u16* uhP = uh + ((size_t)b * NT + t0) * DINNER + d;
    const u16* ulP = ul + ((size_t)b * NT + t0) * DINNER + d;
    u16* yhP = (u16*)uhP;
    u16* ylP = (u16*)ulP;
    const float* bP = xdbl + ((size_t)b * NT + t0) * 128 + DTRANK;
    float h[DSTATE];
    size_t ha = (((size_t)(b * NCHK + c) * DINNER) + d) * DSTATE;
    #pragma unroll
    for (int j = 0; j < 4; ++j) *(f32x4*)&h[j * 4] = *(const f32x4*)(HP + ha + j * 4);
    float dlt = dP[0], zz = zP[0];
    float uu = bf2f(uhP[0]) + bf2f(ulP[0]);
    float Bv[DSTATE], Cv[DSTATE];
    #pragma unroll
    for (int j = 0; j < 4; ++j) {
        *(f32x4*)&Bv[j * 4] = *(const f32x4*)(bP + j * 4);
        *(f32x4*)&Cv[j * 4] = *(const f32x4*)(bP + DSTATE + j * 4);
    }
    for (int t = 0; t < CHKT; ++t) {
        float dlt_n = 0.f, uu_n = 0.f, zz_n = 0.f;
        float Bn[DSTATE], Cn[DSTATE];
        #pragma unroll
        for (int s = 0; s < DSTATE; ++s) { Bn[s] = 0.f; Cn[s] = 0.f; }
        if (t + 1 < CHKT) {
            dlt_n = dP[2 * DINNER]; zz_n = zP[2 * DINNER];
            uu_n = bf2f(uhP[DINNER]) + bf2f(ulP[DINNER]);
            #pragma unroll
            for (int j = 0; j < 4; ++j) {
                *(f32x4*)&Bn[j * 4] = *(const f32x4*)(bP + 128 + j * 4);
                *(f32x4*)&Cn[j * 4] = *(const f32x4*)(bP + 128 + DSTATE + j * 4);
            }
        }
        float du = dlt * uu;
        float p0 = 0.f, p1 = 0.f, p2 = 0.f, p3 = 0.f;
        #pragma unroll
        for (int j = 0; j < 4; ++j) {
            float e0 = exp2f(dlt * aa[j * 4 + 0]);
            float e1 = exp2f(dlt * aa[j * 4 + 1]);
            float e2 = exp2f(dlt * aa[j * 4 + 2]);
            float e3 = exp2f(dlt * aa[j * 4 + 3]);
            h[j * 4 + 0] = fmaf(e0, h[j * 4 + 0], du * Bv[j * 4 + 0]);
            h[j * 4 + 1] = fmaf(e1, h[j * 4 + 1], du * Bv[j * 4 + 1]);
            h[j * 4 + 2] = fmaf(e2, h[j * 4 + 2], du * Bv[j * 4 + 2]);
            h[j * 4 + 3] = fmaf(e3, h[j * 4 + 3], du * Bv[j * 4 + 3]);
            p0 = fmaf(h[j * 4 + 0], Cv[j * 4 + 0], p0);
            p1 = fmaf(h[j * 4 + 1], Cv[j * 4 + 1], p1);
            p2 = fmaf(h[j * 4 + 2], Cv[j * 4 + 2], p2);
            p3 = fmaf(h[j * 4 + 3], Cv[j * 4 + 3], p3);
        }
        float p = (p0 + p1) + (p2 + p3);
        float yv = (p + uu * dp) * siluf(zz);
        u16 hh = f2bf(yv);
        yhP[0] = hh;
        ylP[0] = f2bf(yv - bf2f(hh));
        dP += 2 * DINNER; zP += 2 * DINNER;
        uhP += DINNER; ulP += DINNER; yhP += DINNER; ylP += DINNER;
        bP += 128;
        dlt = dlt_n; zz = zz_n; uu = uu_n;
        #pragma unroll
        for (int s = 0; s < DSTATE; ++s) { Bv[s] = Bn[s]; Cv[s] = Cn[s]; }
    }
}

// ---------------- final fc + silu + transpose to (B,5,T) ----------------
__global__ __launch_bounds__(256) void k_fc(const float* __restrict__ hR,
    const float* __restrict__ w, const float* __restrict__ bias,
    float* __restrict__ out)
{
    int row = blockIdx.x;
    int tid = threadIdx.x;
    const float* p = hR + (size_t)row * DMODEL;
    float acc[NCLASS] = {0.f, 0.f, 0.f, 0.f, 0.f};
    #pragma unroll
    for (int j = 0; j < 6; ++j) {
        int col = tid + j * 256;
        float v = p[col];
        #pragma unroll
        for (int c = 0; c < NCLASS; ++c)
            acc[c] = fmaf(v, w[c * DMODEL + col], acc[c]);
    }
    #pragma unroll
    for (int c = 0; c < NCLASS; ++c)
        #pragma unroll
        for (int off = 1; off < 64; off <<= 1)
            acc[c] += __shfl_xor(acc[c], off);
    __shared__ float red[4][NCLASS];
    int lane = tid & 63, wv = tid >> 6;
    if (lane == 0)
        for (int c = 0; c < NCLASS; ++c) red[wv][c] = acc[c];
    __syncthreads();
    if (tid < NCLASS) {
        float s = red[0][tid] + red[1][tid] + red[2][tid] + red[3][tid] + bias[tid];
        int b = row >> 10, t = row & (NT - 1);
        out[((size_t)b * NCLASS + tid) * NT + t] = siluf(s);
    }
}

extern "C" void kernel_launch(void* const* d_in, const int* in_sizes, int n_in,
                              void* d_out, int out_size, void* d_ws, size_t ws_size,
                              hipStream_t stream)
{
    const float* x      = (const float*)d_in[0];
    const float* c1a_w  = (const float*)d_in[1];
    const float* c1a_b  = (const float*)d_in[2];
    const float* c1b_w  = (const float*)d_in[3];
    const float* c1b_b  = (const float*)d_in[4];
    const float* c1s_w  = (const float*)d_in[5];
    const float* c1s_b  = (const float*)d_in[6];
    const float* c2a_w  = (const float*)d_in[7];
    const float* c2a_b  = (const float*)d_in[8];
    const float* c2b_w  = (const float*)d_in[9];
    const float* c2b_b  = (const float*)d_in[10];
    const float* norm_w = (const float*)d_in[11];
    const float* in_w   = (const float*)d_in[12];
    const float* conv_w = (const float*)d_in[13];
    const float* conv_b = (const float*)d_in[14];
    const float* xproj_w= (const float*)d_in[15];
    const float* dt_w   = (const float*)d_in[16];
    const float* dt_b   = (const float*)d_in[17];
    const float* A_log  = (const float*)d_in[18];
    const float* Dp     = (const float*)d_in[19];
    const float* out_w  = (const float*)d_in[20];
    const float* fc_w   = (const float*)d_in[21];
    const float* fc_b   = (const float*)d_in[22];
    float* outp = (float*)d_out;
    (void)in_sizes; (void)n_in; (void)out_size; (void)ws_size;

    char* base = (char*)d_ws;
    size_t off = 0;
    auto takeB = [&](size_t bytes) { void* p = base + off; off = (off + bytes + 255) & ~(size_t)255; return p; };
    float* HCAT = (float*)takeB((size_t)NB * NDIM * NT * 4);
    float* XZ   = (float*)takeB((size_t)MROWS * 2 * DINNER * 4);
    float* RES  = (float*)takeB((size_t)MROWS * DMODEL * 4);
    u16*   XNh  = (u16*)takeB((size_t)MROWS * DMODEL * 2);
    u16*   XNl  = (u16*)takeB((size_t)MROWS * DMODEL * 2);
    u16*   Uh   = (u16*)takeB((size_t)MROWS * DINNER * 2);
    u16*   Ul   = (u16*)takeB((size_t)MROWS * DINNER * 2);
    float* XDBL = (float*)takeB((size_t)MROWS * 128 * 4);
    float* XPART= (float*)takeB((size_t)4 * MROWS * 128 * 4);
    u16*   XDh  = (u16*)takeB((size_t)MROWS * 128 * 2);
    u16*   XDl  = (u16*)takeB((size_t)MROWS * 128 * 2);
    u16*   Wh   = (u16*)takeB((size_t)9437184 * 2);
    u16*   Wl   = (u16*)takeB((size_t)9437184 * 2);
    float* HP   = (float*)takeB((size_t)NB * NCHK * DINNER * DSTATE * 4);  // 25.2 MB
    float* SS   = (float*)takeB((size_t)NB * NCHK * DINNER * 4);           // 1.6 MB
    u16*   CW1h = (u16*)takeB(18432);
    u16*   CW1l = (u16*)takeB(18432);
    u16*   CW2h = (u16*)takeB(18432);
    u16*   CW2l = (u16*)takeB(18432);
    u16*   CW3h = (u16*)takeB(18432);
    u16*   CW3l = (u16*)takeB(18432);
    u16*   ZPAD = (u16*)takeB(256);

    u16* T1h = (u16*)XZ;
    u16* T1l = T1h + (size_t)NB * NDIM * NT * 32;
    u16* T3h = (u16*)XZ;
    u16* T3l = T3h + (size_t)NB * NDIM * NT * 32;
    u16* P1h = Uh;
    u16* P1l = Ul;

    const int n1 = NB * NDIM * NT;
    k_zero<<<1, 128, 0, stream>>>(ZPAD);
    k_prep  <<<(n1 + 255) / 256, 256, 0, stream>>>(x, HCAT);
    k_wconv<<<36, 256, 0, stream>>>(c1b_w, CW1h, CW1l);
    k_wconv<<<36, 256, 0, stream>>>(c2a_w, CW2h, CW2l);
    k_wconv<<<36, 256, 0, stream>>>(c2b_w, CW3h, CW3l);
    k_conv1a<<<(n1 + 255) / 256, 256, 0, stream>>>(HCAT, c1a_w, c1a_b, T1h, T1l);
    k_convmfma<0><<<dim3(16, 96, NB), 256, 0, stream>>>(
        T1h, T1l, CW1h, CW1l, HCAT, c1s_w, c1s_b, nullptr, nullptr,
        c1b_b, P1h, P1l, nullptr, ZPAD);
    k_convmfma<1><<<dim3(16, 48, NB), 256, 0, stream>>>(
        P1h, P1l, CW2h, CW2l, nullptr, nullptr, nullptr, nullptr, nullptr,
        c2a_b, T3h, T3l, nullptr, ZPAD);
    k_convmfma<2><<<dim3(16, 48, NB), 256, 0, stream>>>(
        T3h, T3l, CW3h, CW3l, nullptr, nullptr, nullptr, P1h, P1l,
        c2b_b, nullptr, nullptr, RES, ZPAD);

    for (int l = 0; l < NLAYER; ++l) {
        k_rmsnorm<<<MROWS, 256, 0, stream>>>(RES, norm_w + (size_t)l * DMODEL, XNh, XNl);
        k_split<<<(9437184 / 4 + 255) / 256, 256, 0, stream>>>(
            in_w + (size_t)l * 2 * DINNER * DMODEL, Wh, Wl, 9437184 / 4);
        k_gemm_mfma<0><<<dim3(2 * DINNER / 128, MROWS / 128, 1), 256, 0, stream>>>(
            XNh, XNl, DMODEL, Wh, Wl, DMODEL, XZ, 2 * DINNER, DMODEL, nullptr, 0);
        k_conv1d<<<(NB * NT * (DINNER / 4) + 255) / 256, 256, 0, stream>>>(
            XZ, conv_w + (size_t)l * DINNER * 4, conv_b + (size_t)l * DINNER, Uh, Ul);
        k_split<<<(393216 / 4 + 255) / 256, 256, 0, stream>>>(
            xproj_w + (size_t)l * 128 * DINNER, Wh, Wl, 393216 / 4);
        k_gemm_mfma<0><<<dim3(1, MROWS / 128, 4), 256, 0, stream>>>(
            Uh, Ul, DINNER, Wh, Wl, DINNER, XPART, 128, DINNER, nullptr, (size_t)MROWS * 128);
        k_reduce4<<<(MROWS * 128 + 255) / 256, 256, 0, stream>>>(XPART, XDBL);
        k_split<<<(MROWS * 128 / 4 + 255) / 256, 256, 0, stream>>>(XDBL, XDh, XDl, MROWS * 128 / 4);
        k_wsplit_pad<<<(DINNER * 128 + 255) / 256, 256, 0, stream>>>(
            dt_w + (size_t)l * DINNER * DTRANK, Wh, Wl);
        k_gemm_mfma<1><<<dim3(DINNER / 128, MROWS / 128, 1), 256, 0, stream>>>(
            XDh, XDl, 128, Wh, Wl, 128, XZ, 2 * DINNER, 128,
            dt_b + (size_t)l * DINNER, 0);
        k_scan_p1<<<dim3(DINNER / 256, NCHK, NB), 256, 0, stream>>>(
            XZ, Uh, Ul, XDBL, A_log + (size_t)l * DINNER * DSTATE, HP, SS);
        k_scan_p2<<<(NB * DINNER * DSTATE + 255) / 256, 256, 0, stream>>>(
            HP, SS, A_log + (size_t)l * DINNER * DSTATE);
        k_scan_p3<<<dim3(DINNER / 256, NCHK, NB), 256, 0, stream>>>(
            XZ, Uh, Ul, XDBL, A_log + (size_t)l * DINNER * DSTATE,
            Dp + (size_t)l * DINNER, HP);
        k_split<<<(4718592 / 4 + 255) / 256, 256, 0, stream>>>(
            out_w + (size_t)l * DMODEL * DINNER, Wh, Wl, 4718592 / 4);
        k_gemm_mfma<2><<<dim3(DMODEL / 128, MROWS / 128, 1), 256, 0, stream>>>(
            Uh, Ul, DINNER, Wh, Wl, DINNER, RES, DMODEL, DINNER, nullptr, 0);
    }
    k_fc<<<MROWS, 256, 0, stream>>>(RES, fc_w, fc_b, outp);
}